// Round 11
// baseline (545.686 us; speedup 1.0000x reference)
//
#include <hip/hip_runtime.h>
#include <math.h>

#define N_NODES 50000
#define N_TILES 3125      // N_NODES / 16 exactly
#define N_EDGES 1600000
#define F_IN 128
#define C 64
#define EF 64
#define N_GRAPHS 512
#define MLP_DIM 128
#define N_CLASSES 10
#define EPS 1e-5f
#define NB 196            // coarse buckets: dst>>8, 256 nodes each
#define CAPB 16384        // fixed bucket capacity (mean 8192, std ~90 -> safe)
#define CHUNK 4096        // edges per pass-1 block
#define NSLICE 8          // bn-stat atomic slices

typedef __attribute__((ext_vector_type(8))) _Float16 half8;
typedef __attribute__((ext_vector_type(2))) _Float16 half2v;
typedef __attribute__((ext_vector_type(4))) float floatx4;
typedef __attribute__((ext_vector_type(4))) unsigned uintx4;

union Uh { uintx4 v; half2v h[4]; half8 h8; };

__device__ __forceinline__ unsigned short f2h(float a) {
    union { _Float16 f; unsigned short u; } c;
    c.f = (_Float16)a;   // RNE
    return c.u;
}
__device__ __forceinline__ float h2f(unsigned short u) {
    union { unsigned short u; _Float16 f; } c;
    c.u = u;
    return (float)c.f;
}
__device__ __forceinline__ half2v pk2(float a, float b) {
    auto t = __builtin_amdgcn_cvt_pkrtz(a, b);   // __fp16 vec2 -> bit-cast (R6 lesson)
    union { decltype(t) i; half2v o; } c;
    c.i = t;
    return c.o;
}

// ======== sort pass 1: bin edges into fixed-capacity buckets + per-node degree hist ========
__global__ __launch_bounds__(256) void pass1_kernel(const int* __restrict__ src,
                                                    const int* __restrict__ dst,
                                                    int* __restrict__ gcur,
                                                    unsigned* __restrict__ keys,
                                                    int* __restrict__ cnt) {
    __shared__ int lcnt[NB], lbase[NB], lcnt2[NB];
    int tid = threadIdx.x;
    int e0 = blockIdx.x * CHUNK;
    unsigned k[CHUNK / 256];
    int bk[CHUNK / 256];
    for (int i = tid; i < NB; i += 256) lcnt[i] = 0;
    __syncthreads();
#pragma unroll
    for (int i = 0; i < CHUNK / 256; i++) {
        int e = e0 + i * 256 + tid;
        if (e < N_EDGES) {
            int d = dst[e];
            k[i] = ((unsigned)d << 16) | (unsigned)src[e];
            bk[i] = d >> 8;
            atomicAdd(&lcnt[bk[i]], 1);
            atomicAdd(&cnt[d], 1);            // per-node degree (was node_count_kernel)
        } else bk[i] = -1;
    }
    __syncthreads();
    for (int i = tid; i < NB; i += 256) {
        int c = lcnt[i];
        lbase[i] = c ? atomicAdd(&gcur[i], c) : 0;
        lcnt2[i] = 0;
    }
    __syncthreads();
#pragma unroll
    for (int i = 0; i < CHUNK / 256; i++) {
        if (bk[i] >= 0) {
            int r = atomicAdd(&lcnt2[bk[i]], 1);
            keys[(size_t)bk[i] * CAPB + lbase[bk[i]] + r] = k[i];
        }
    }
}

// ===== row_start via per-bucket padded scan + atomic ticket (order-free: edge uses cnt for ends) =====
__global__ __launch_bounds__(256) void rowstart_kernel(const int* __restrict__ cnt,
                                                       int* __restrict__ gtotal,
                                                       int* __restrict__ row_start) {
    __shared__ int loc[256];
    __shared__ int base;
    int tid = threadIdx.x, b = blockIdx.x;
    int node = b * 256 + tid;
    int pc = (node < N_NODES) ? ((cnt[node] + 15) & ~15) : 0;
    loc[tid] = pc;
    __syncthreads();
    for (int off = 1; off < 256; off <<= 1) {
        int t = (tid >= off) ? loc[tid - off] : 0;
        __syncthreads();
        loc[tid] += t;
        __syncthreads();
    }
    if (tid == 255) base = atomicAdd(gtotal, loc[255]);
    __syncthreads();
    if (node < N_NODES) row_start[node] = base + loc[tid] - pc;
}

// ===== scatter: 4 blocks/bucket, global cursor atomics; pads stay 0xFFFF (pre-memset sentinel) =====
__global__ __launch_bounds__(256) void scatter4_kernel(const unsigned* __restrict__ keys,
                                                       const int* __restrict__ gcur,
                                                       const int* __restrict__ row_start,
                                                       int* __restrict__ cursor,
                                                       unsigned short* __restrict__ sorted_src) {
    int b = blockIdx.x >> 2, part = blockIdx.x & 3;
    int nk = gcur[b];
    int chunk = (nk + 3) >> 2;
    int beg = part * chunk;
    int end = beg + chunk; if (end > nk) end = nk;
    const unsigned* kb = keys + (size_t)b * CAPB;
    for (int p = beg + threadIdx.x; p < end; p += 256) {
        unsigned k = kb[p];
        int d = k >> 16;
        int r = atomicAdd(&cursor[d], 1);
        sorted_src[row_start[d] + r] = (unsigned short)(k & 0xFFFFu);
    }
}

// ============ fc0 via MFMA: h0[16-node tile] = x @ fc0_w + b (f16 out) + BN stats ============
__global__ __launch_bounds__(256, 3) void fc0_mfma_kernel(const float* __restrict__ x,
                                                          const float* __restrict__ w,
                                                          const float* __restrict__ b,
                                                          unsigned short* __restrict__ h0,
                                                          float* __restrict__ bns) {
    __shared__ float bl1[4][64], bl2[4][64];
    int tid = threadIdx.x, lane = tid & 63, wid = tid >> 6;
    int q = lane >> 4, cl = lane & 15, kq = q * 8;

    Uh wf[4][4];
#pragma unroll
    for (int kh = 0; kh < 4; kh++)
#pragma unroll
        for (int cb = 0; cb < 4; cb++)
#pragma unroll
            for (int j = 0; j < 4; j++) {
                int k0 = kh * 32 + kq + 2 * j;
                int col = cb * 16 + cl;
                wf[kh][cb].h[j] = pk2(w[k0 * 64 + col], w[(k0 + 1) * 64 + col]);
            }
    float bv[4];
#pragma unroll
    for (int cb = 0; cb < 4; cb++) bv[cb] = b[cb * 16 + cl];
    float s1[4] = {0, 0, 0, 0}, s2[4] = {0, 0, 0, 0};

    for (int t = blockIdx.x * 4 + wid; t < N_TILES; t += gridDim.x * 4) {
        int nb = t * 16;
        floatx4 acc[4] = {{0,0,0,0},{0,0,0,0},{0,0,0,0},{0,0,0,0}};
#pragma unroll
        for (int kh = 0; kh < 4; kh++) {
            const float* xr = x + (size_t)(nb + cl) * F_IN + kh * 32 + kq;
            floatx4 xa = *(const floatx4*)xr;
            floatx4 xb = *(const floatx4*)(xr + 4);
            Uh xf;
            xf.h[0] = pk2(xa.x, xa.y); xf.h[1] = pk2(xa.z, xa.w);
            xf.h[2] = pk2(xb.x, xb.y); xf.h[3] = pk2(xb.z, xb.w);
#pragma unroll
            for (int cb = 0; cb < 4; cb++)
                acc[cb] = __builtin_amdgcn_mfma_f32_16x16x32_f16(xf.h8, wf[kh][cb].h8, acc[cb], 0, 0, 0);
        }
#pragma unroll
        for (int cb = 0; cb < 4; cb++)
#pragma unroll
            for (int r = 0; r < 4; r++) {
                float v = acc[cb][r] + bv[cb];            // node = nb+q*4+r, col = cb*16+cl
                h0[(size_t)(nb + q * 4 + r) * 64 + cb * 16 + cl] = f2h(v);
                s1[cb] += v; s2[cb] += v * v;
            }
    }
#pragma unroll
    for (int cb = 0; cb < 4; cb++) {
        s1[cb] += __shfl_xor(s1[cb], 16); s1[cb] += __shfl_xor(s1[cb], 32);
        s2[cb] += __shfl_xor(s2[cb], 16); s2[cb] += __shfl_xor(s2[cb], 32);
    }
    if (lane < 16) {
#pragma unroll
        for (int cb = 0; cb < 4; cb++) { bl1[wid][cb * 16 + lane] = s1[cb]; bl2[wid][cb * 16 + lane] = s2[cb]; }
    }
    __syncthreads();
    if (tid < 64) {
        float a  = bl1[0][tid] + bl1[1][tid] + bl1[2][tid] + bl1[3][tid];
        float c2 = bl2[0][tid] + bl2[1][tid] + bl2[2][tid] + bl2[3][tid];
        int sl = blockIdx.x & (NSLICE - 1);
        atomicAdd(&bns[sl * 128 + tid], a);
        atomicAdd(&bns[sl * 128 + 64 + tid], c2);
    }
}

// ============ ab via MFMA: A = bn(h)@WA + cA, B = bn(h)@WB + cB (both f16) ============
__global__ __launch_bounds__(256, 4) void ab_mfma_kernel(const unsigned short* __restrict__ h,
                                                         const float* __restrict__ bns,
                                                         const float* __restrict__ g,
                                                         const float* __restrict__ bb,
                                                         const float* __restrict__ w1,
                                                         const float* __restrict__ b1,
                                                         unsigned short* __restrict__ A,
                                                         unsigned short* __restrict__ Bb) {
    __shared__ float scale[64], shift[64], cab[128];
    int tid = threadIdx.x, lane = tid & 63, wid = tid >> 6;
    int q = lane >> 4, cl = lane & 15, kq = q * 8;

    if (tid < 64) {
        float s1v = 0.f, s2v = 0.f;
#pragma unroll
        for (int s = 0; s < NSLICE; s++) { s1v += bns[s * 128 + tid]; s2v += bns[s * 128 + 64 + tid]; }
        float mu  = s1v * (1.0f / N_NODES);
        float var = s2v * (1.0f / N_NODES) - mu * mu;
        float sc  = g[tid] * rsqrtf(var + EPS);
        scale[tid] = sc;
        shift[tid] = bb[tid] - mu * sc;
    }
    __syncthreads();
    if (tid < 128) {
        int j = tid & 63;
        float acc = (tid < 64) ? b1[j] : 0.f;
        for (int k = 0; k < 64; k++) {
            float wa_ = w1[k * EF + j], wb_ = w1[(64 + k) * EF + j];
            acc = fmaf(shift[k], (tid < 64) ? (wa_ - wb_) : wb_, acc);
        }
        cab[tid] = acc;
    }
    Uh wa[2][4], wb[2][4];
#pragma unroll
    for (int kh = 0; kh < 2; kh++)
#pragma unroll
        for (int cb = 0; cb < 4; cb++)
#pragma unroll
            for (int j = 0; j < 4; j++) {
                int k0 = kh * 32 + kq + 2 * j;
                int col = cb * 16 + cl;
                float sa = scale[k0], sb = scale[k0 + 1];
                float a0 = w1[k0 * EF + col], b0 = w1[(64 + k0) * EF + col];
                float a1 = w1[(k0 + 1) * EF + col], b1v = w1[(64 + k0 + 1) * EF + col];
                wa[kh][cb].h[j] = pk2(sa * (a0 - b0), sb * (a1 - b1v));
                wb[kh][cb].h[j] = pk2(sa * b0, sb * b1v);
            }
    __syncthreads();
    float cav[4], cbv[4];
#pragma unroll
    for (int cb = 0; cb < 4; cb++) { cav[cb] = cab[cb * 16 + cl]; cbv[cb] = cab[64 + cb * 16 + cl]; }

    for (int t = blockIdx.x * 4 + wid; t < N_TILES; t += gridDim.x * 4) {
        int nb = t * 16;
        const unsigned short* hrow = h + (size_t)(nb + cl) * 64 + kq;
        Uh h0f, h1f;
        h0f.v = *(const uintx4*)hrow;
        h1f.v = *(const uintx4*)(hrow + 32);
        floatx4 accA[4] = {{0,0,0,0},{0,0,0,0},{0,0,0,0},{0,0,0,0}};
        floatx4 accB[4] = {{0,0,0,0},{0,0,0,0},{0,0,0,0},{0,0,0,0}};
#pragma unroll
        for (int cb = 0; cb < 4; cb++) {
            accA[cb] = __builtin_amdgcn_mfma_f32_16x16x32_f16(h0f.h8, wa[0][cb].h8, accA[cb], 0, 0, 0);
            accB[cb] = __builtin_amdgcn_mfma_f32_16x16x32_f16(h0f.h8, wb[0][cb].h8, accB[cb], 0, 0, 0);
            accA[cb] = __builtin_amdgcn_mfma_f32_16x16x32_f16(h1f.h8, wa[1][cb].h8, accA[cb], 0, 0, 0);
            accB[cb] = __builtin_amdgcn_mfma_f32_16x16x32_f16(h1f.h8, wb[1][cb].h8, accB[cb], 0, 0, 0);
        }
#pragma unroll
        for (int cb = 0; cb < 4; cb++)
#pragma unroll
            for (int r = 0; r < 4; r++) {
                size_t o = (size_t)(nb + q * 4 + r) * 64 + cb * 16 + cl;
                A[o]  = f2h(accA[cb][r] + cav[cb]);
                Bb[o] = f2h(accB[cb][r] + cbv[cb]);
            }
    }
}

// ============ EdgeConv via f16 MFMA: 2-node interleave, sentinel pads, cnt-based ends ============
// Plain __launch_bounds__(256): no wave cap -> no spill risk (R7 lesson). ~2 gathers always in flight.
__global__ __launch_bounds__(256) void edge_mfma_kernel(
        const unsigned short* __restrict__ A, const unsigned short* __restrict__ Bb,
        const int* __restrict__ row_start, const int* __restrict__ cnt,
        const unsigned short* __restrict__ sorted_src,
        const float* __restrict__ w2, const float* __restrict__ b2,
        unsigned short* __restrict__ catp, float* __restrict__ bnsNext) {
    __shared__ float r1s[4][64], r2s[4][64];
    int tid = threadIdx.x, lane = tid & 63, wid = tid >> 6;
    int kq = (lane >> 4) * 8;
    int cl = lane & 15;

    Uh bfr[2][4];
#pragma unroll
    for (int kh = 0; kh < 2; kh++)
#pragma unroll
        for (int cb = 0; cb < 4; cb++)
#pragma unroll
            for (int j = 0; j < 4; j++) {
                _Float16 w0 = (_Float16)w2[(kh * 32 + kq + 2 * j) * 64 + cb * 16 + cl];
                _Float16 w1 = (_Float16)w2[(kh * 32 + kq + 2 * j + 1) * 64 + cb * 16 + cl];
                bfr[kh][cb].h[j] = half2v{w0, w1};
            }
    float b2j = b2[lane];
    float s1 = 0.f, s2 = 0.f;
    const half2v zeroh = {(_Float16)0.f, (_Float16)0.f};

    auto gather = [&](int p, uintx4& u0, uintx4& u1) {
        int srcm = sorted_src[p + cl];
        int ent0 = __shfl(srcm, lane & 48);          // entry 0 of this tile (always real)
        srcm = (srcm == 0xFFFF) ? ent0 : srcm;       // sentinel pad -> duplicate entry 0 (max idempotent)
        const unsigned short* brow = Bb + (size_t)srcm * 64 + kq;
        u0 = *(const uintx4*)(brow);
        u1 = *(const uintx4*)(brow + 32);
    };

    for (int nb = blockIdx.x * 8 + wid * 2; nb < N_NODES; nb += gridDim.x * 8) {
        int n0 = nb, n1 = nb + 1;                    // N_NODES even -> n1 always valid
        int rs0 = row_start[n0], rs1 = row_start[n1];
        int e0p = rs0 + ((cnt[n0] + 15) & ~15);
        int e1p = rs1 + ((cnt[n1] + 15) & ~15);
        const unsigned short* ar0 = A + (size_t)n0 * 64 + kq;
        const unsigned short* ar1 = A + (size_t)n1 * 64 + kq;
        Uh a00, a01, a10, a11;
        a00.v = *(const uintx4*)ar0; a01.v = *(const uintx4*)(ar0 + 32);
        a10.v = *(const uintx4*)ar1; a11.v = *(const uintx4*)(ar1 + 32);
        floatx4 rm0[4], rm1[4];
#pragma unroll
        for (int i = 0; i < 4; i++) {
            rm0[i] = floatx4{-INFINITY, -INFINITY, -INFINITY, -INFINITY};
            rm1[i] = rm0[i];
        }

        auto tile = [&](Uh& aa0, Uh& aa1, floatx4 (&rm)[4], uintx4 u0, uintx4 u1) {
            Uh b0u, b1u, f0, f1;
            b0u.v = u0; b1u.v = u1;
#pragma unroll
            for (int j = 0; j < 4; j++) {            // v_pk_add_f16 + v_pk_max_f16
                f0.h[j] = __builtin_elementwise_max(aa0.h[j] + b0u.h[j], zeroh);
                f1.h[j] = __builtin_elementwise_max(aa1.h[j] + b1u.h[j], zeroh);
            }
#pragma unroll
            for (int cb = 0; cb < 4; cb++) {
                floatx4 acc = {0.f, 0.f, 0.f, 0.f};
                acc = __builtin_amdgcn_mfma_f32_16x16x32_f16(f0.h8, bfr[0][cb].h8, acc, 0, 0, 0);
                acc = __builtin_amdgcn_mfma_f32_16x16x32_f16(f1.h8, bfr[1][cb].h8, acc, 0, 0, 0);
                rm[cb] = __builtin_elementwise_max(rm[cb], acc);
            }
        };

        int p0 = rs0, p1 = rs1;
        while (p0 < e0p || p1 < e1p) {               // wave-uniform conditions
            uintx4 x0, x1, y0, y1;
            bool d0 = p0 < e0p, d1 = p1 < e1p;
            if (d0) gather(p0, x0, x1);
            if (d1) gather(p1, y0, y1);
            if (d0) { tile(a00, a01, rm0, x0, x1); p0 += 16; }
            if (d1) { tile(a10, a11, rm1, y0, y1); p1 += 16; }
        }

        auto finish = [&](floatx4 (&rm)[4], int n) {
            float v0 = fmaxf(fmaxf(rm[0].x, rm[0].y), fmaxf(rm[0].z, rm[0].w));
            float v1 = fmaxf(fmaxf(rm[1].x, rm[1].y), fmaxf(rm[1].z, rm[1].w));
            float v2 = fmaxf(fmaxf(rm[2].x, rm[2].y), fmaxf(rm[2].z, rm[2].w));
            float v3 = fmaxf(fmaxf(rm[3].x, rm[3].y), fmaxf(rm[3].z, rm[3].w));
            v0 = fmaxf(v0, __shfl_xor(v0, 16)); v0 = fmaxf(v0, __shfl_xor(v0, 32));
            v1 = fmaxf(v1, __shfl_xor(v1, 16)); v1 = fmaxf(v1, __shfl_xor(v1, 32));
            v2 = fmaxf(v2, __shfl_xor(v2, 16)); v2 = fmaxf(v2, __shfl_xor(v2, 32));
            v3 = fmaxf(v3, __shfl_xor(v3, 16)); v3 = fmaxf(v3, __shfl_xor(v3, 32));
            float vs = (lane & 32) ? ((lane & 16) ? v3 : v2) : ((lane & 16) ? v1 : v0);
            float v = fmaxf(vs + b2j, 0.f);          // -inf (empty node) -> 0
            catp[(size_t)n * 64 + lane] = f2h(v);
            s1 += v; s2 += v * v;
        };
        finish(rm0, n0);
        finish(rm1, n1);
    }

    if (bnsNext) {
        r1s[wid][lane] = s1; r2s[wid][lane] = s2;
        __syncthreads();
        if (tid < 64) {
            float a  = r1s[0][tid] + r1s[1][tid] + r1s[2][tid] + r1s[3][tid];
            float c2 = r2s[0][tid] + r2s[1][tid] + r2s[2][tid] + r2s[3][tid];
            int sl = blockIdx.x & (NSLICE - 1);
            atomicAdd(&bnsNext[sl * 128 + tid], a);
            atomicAdd(&bnsNext[sl * 128 + 64 + tid], c2);
        }
    }
}

// ============================ fused graph mean pool + MLP head + log_softmax ============================
__global__ __launch_bounds__(192) void poolhead_kernel(const unsigned short* __restrict__ cat0,
                                                       const unsigned short* __restrict__ cat1,
                                                       const unsigned short* __restrict__ cat2,
                                                       const int* __restrict__ batch,
                                                       const float* __restrict__ fc1w,
                                                       const float* __restrict__ fc1b,
                                                       const float* __restrict__ fc2w,
                                                       const float* __restrict__ fc2b,
                                                       float* __restrict__ out) {
    __shared__ int se[2];
    __shared__ float p[192];
    __shared__ float hid[128];
    __shared__ float z[10];
    __shared__ float lse;
    int g = blockIdx.x, tid = threadIdx.x;  // 192 threads
    if (tid < 2) {
        int target = g + tid;
        int lo = 0, hi = N_NODES;
        while (lo < hi) { int mid = (lo + hi) >> 1; if (batch[mid] < target) lo = mid + 1; else hi = mid; }
        se[tid] = lo;
    }
    __syncthreads();
    int s = se[0], e = se[1];
    const unsigned short* plane = (tid < 64) ? cat0 : ((tid < 128) ? cat1 : cat2);
    int col = tid & 63;
    float a0 = 0.f, a1 = 0.f, a2 = 0.f, a3 = 0.f;   // 4-way ILP in the pooling loop
    int r = s;
    for (; r + 4 <= e; r += 4) {
        a0 += h2f(plane[(size_t)(r + 0) * 64 + col]);
        a1 += h2f(plane[(size_t)(r + 1) * 64 + col]);
        a2 += h2f(plane[(size_t)(r + 2) * 64 + col]);
        a3 += h2f(plane[(size_t)(r + 3) * 64 + col]);
    }
    for (; r < e; r++) a0 += h2f(plane[(size_t)r * 64 + col]);
    float acc = (a0 + a1) + (a2 + a3);
    float denom = (e > s) ? (float)(e - s) : 1.0f;
    p[tid] = acc / denom;
    __syncthreads();
    if (tid < MLP_DIM) {
        float a = fc1b[tid];
        for (int k = 0; k < 192; k++) a = fmaf(p[k], fc1w[k * 128 + tid], a);
        hid[tid] = fmaxf(a, 0.f);
    }
    __syncthreads();
    if (tid < N_CLASSES) {
        float a = fc2b[tid];
        for (int k = 0; k < 128; k++) a = fmaf(hid[k], fc2w[k * 10 + tid], a);
        z[tid] = a;
    }
    __syncthreads();
    if (tid == 0) {
        float m = z[0];
        for (int i = 1; i < 10; i++) m = fmaxf(m, z[i]);
        float sm = 0.f;
        for (int i = 0; i < 10; i++) sm += expf(z[i] - m);
        lse = m + logf(sm);
    }
    __syncthreads();
    if (tid < N_CLASSES) out[g * 10 + tid] = z[tid] - lse;
}

// ============================ launch ============================
extern "C" void kernel_launch(void* const* d_in, const int* in_sizes, int n_in,
                              void* d_out, int out_size, void* d_ws, size_t ws_size,
                              hipStream_t stream) {
    (void)in_sizes; (void)n_in; (void)out_size; (void)ws_size;
    const float* x    = (const float*)d_in[0];
    const int*   ei   = (const int*)d_in[1];
    const int*   batch= (const int*)d_in[2];
    const float* fc0w = (const float*)d_in[3];
    const float* fc0b = (const float*)d_in[4];
    const float* fc1w = (const float*)d_in[5];
    const float* fc1b = (const float*)d_in[6];
    const float* fc2w = (const float*)d_in[7];
    const float* fc2b = (const float*)d_in[8];
    const int* src = ei;
    const int* dst = ei + N_EDGES;
    float* out = (float*)d_out;

    char* w = (char*)d_ws;
    size_t off = 0;
    auto alloc = [&](size_t bytes) -> void* {
        void* p = w + off;
        off = (off + bytes + 255) & ~(size_t)255;
        return p;
    };
    const size_t MAX_PAD_EDGES = (size_t)N_EDGES + 16 * (size_t)N_NODES;

    // zeroed-every-launch block: gcur[NB] | gtotal | bns[3][NSLICE][128] | cnt[N] | cursor[N]
    const size_t BNS_OFF = 1280;
    const size_t CNT_OFF = BNS_OFF + 3 * NSLICE * 128 * 4;
    const size_t CUR_OFF = CNT_OFF + (size_t)N_NODES * 4;
    const size_t ZBYTES  = CUR_OFF + (size_t)N_NODES * 4;
    char* zbase = (char*)alloc(ZBYTES);
    int*   gcur   = (int*)zbase;
    int*   gtotal = (int*)(zbase + 1024);
    float* bnsAll = (float*)(zbase + BNS_OFF);
    int*   cnt    = (int*)(zbase + CNT_OFF);
    int*   cursor = (int*)(zbase + CUR_OFF);

    unsigned short* cat0 = (unsigned short*)alloc((size_t)N_NODES * 64 * 2);  // 6.4 MB/plane (f16)
    unsigned short* cat1 = (unsigned short*)alloc((size_t)N_NODES * 64 * 2);
    unsigned short* cat2 = (unsigned short*)alloc((size_t)N_NODES * 64 * 2);
    unsigned short* h0   = (unsigned short*)alloc((size_t)N_NODES * 64 * 2);
    unsigned short* Ae   = (unsigned short*)alloc((size_t)N_NODES * 64 * 2);
    unsigned short* Be   = (unsigned short*)alloc((size_t)N_NODES * 64 * 2);
    unsigned* keys = (unsigned*)alloc((size_t)NB * CAPB * 4);    // 12.85 MB
    unsigned short* sorted_src = (unsigned short*)alloc(MAX_PAD_EDGES * 2);  // 4.8 MB
    int*   row_start = (int*)alloc((size_t)N_NODES * 4);

    (void)hipMemsetAsync(zbase, 0, ZBYTES, stream);
    (void)hipMemsetAsync(sorted_src, 0xFF, MAX_PAD_EDGES * 2, stream);  // sentinel pads

    // --- sort: pass1 (bin + degree hist) -> rowstart (ticket scan) -> scatter4 ---
    pass1_kernel<<<(N_EDGES + CHUNK - 1) / CHUNK, 256, 0, stream>>>(src, dst, gcur, keys, cnt);
    rowstart_kernel<<<NB, 256, 0, stream>>>(cnt, gtotal, row_start);
    scatter4_kernel<<<NB * 4, 256, 0, stream>>>(keys, gcur, row_start, cursor, sorted_src);

    fc0_mfma_kernel<<<782, 256, 0, stream>>>(x, fc0w, fc0b, h0, bnsAll);

    unsigned short* planes[3] = {cat0, cat1, cat2};
    for (int blk = 0; blk < 3; blk++) {
        const float* g  = (const float*)d_in[9 + 6 * blk];
        const float* bb = (const float*)d_in[10 + 6 * blk];
        const float* w1 = (const float*)d_in[11 + 6 * blk];
        const float* b1 = (const float*)d_in[12 + 6 * blk];
        const float* w2 = (const float*)d_in[13 + 6 * blk];
        const float* b2 = (const float*)d_in[14 + 6 * blk];
        const unsigned short* hsrc = (blk == 0) ? h0 : planes[blk - 1];

        ab_mfma_kernel<<<782, 256, 0, stream>>>(hsrc, bnsAll + blk * NSLICE * 128,
                                                g, bb, w1, b1, Ae, Be);
        edge_mfma_kernel<<<2048, 256, 0, stream>>>(
            Ae, Be, row_start, cnt, sorted_src, w2, b2, planes[blk],
            (blk < 2) ? (bnsAll + (blk + 1) * NSLICE * 128) : nullptr);
    }

    poolhead_kernel<<<N_GRAPHS, 192, 0, stream>>>(cat0, cat1, cat2, batch,
                                                  fc1w, fc1b, fc2w, fc2b, out);
}

// Round 12
// 468.469 us; speedup vs baseline: 1.1648x; 1.1648x over previous
//
#include <hip/hip_runtime.h>
#include <math.h>

#define N_NODES 50000
#define N_TILES 3125      // N_NODES / 16 exactly
#define N_EDGES 1600000
#define F_IN 128
#define C 64
#define EF 64
#define N_GRAPHS 512
#define MLP_DIM 128
#define N_CLASSES 10
#define EPS 1e-5f
#define NB 196            // coarse buckets: dst>>8, 256 nodes each
#define CAPB 16384        // fixed bucket capacity (mean 8192, std ~90 -> safe)
#define CHUNK 4096        // edges per pass-1 block
#define NSLICE 8          // bn-stat atomic slices

typedef __attribute__((ext_vector_type(8))) _Float16 half8;
typedef __attribute__((ext_vector_type(2))) _Float16 half2v;
typedef __attribute__((ext_vector_type(4))) float floatx4;
typedef __attribute__((ext_vector_type(4))) unsigned uintx4;

union Uh { uintx4 v; half2v h[4]; half8 h8; };

__device__ __forceinline__ unsigned short f2h(float a) {
    union { _Float16 f; unsigned short u; } c;
    c.f = (_Float16)a;   // RNE
    return c.u;
}
__device__ __forceinline__ float h2f(unsigned short u) {
    union { unsigned short u; _Float16 f; } c;
    c.u = u;
    return (float)c.f;
}
__device__ __forceinline__ half2v pk2(float a, float b) {
    auto t = __builtin_amdgcn_cvt_pkrtz(a, b);   // __fp16 vec2 -> bit-cast (R6 lesson)
    union { decltype(t) i; half2v o; } c;
    c.i = t;
    return c.o;
}

// ==================== sort pass 1: bin edges into fixed-capacity buckets ====================
// NO per-node global atomics here — R11 showed 1.6M random atomicAdds cost 57 MB writeback.
__global__ __launch_bounds__(256) void pass1_kernel(const int* __restrict__ src,
                                                    const int* __restrict__ dst,
                                                    int* __restrict__ gcur,
                                                    unsigned* __restrict__ keys) {
    __shared__ int lcnt[NB], lbase[NB], lcnt2[NB];
    int tid = threadIdx.x;
    int e0 = blockIdx.x * CHUNK;
    unsigned k[CHUNK / 256];
    int bk[CHUNK / 256];
    for (int i = tid; i < NB; i += 256) lcnt[i] = 0;
    __syncthreads();
#pragma unroll
    for (int i = 0; i < CHUNK / 256; i++) {
        int e = e0 + i * 256 + tid;
        if (e < N_EDGES) {
            int d = dst[e];
            k[i] = ((unsigned)d << 16) | (unsigned)src[e];
            bk[i] = d >> 8;
            atomicAdd(&lcnt[bk[i]], 1);
        } else bk[i] = -1;
    }
    __syncthreads();
    for (int i = tid; i < NB; i += 256) {
        int c = lcnt[i];
        lbase[i] = c ? atomicAdd(&gcur[i], c) : 0;
        lcnt2[i] = 0;
    }
    __syncthreads();
#pragma unroll
    for (int i = 0; i < CHUNK / 256; i++) {
        if (bk[i] >= 0) {
            int r = atomicAdd(&lcnt2[bk[i]], 1);
            keys[(size_t)bk[i] * CAPB + lbase[bk[i]] + r] = k[i];
        }
    }
}

// ==================== per-node degree + per-bucket padded sums (LDS histogram) ====================
__global__ __launch_bounds__(256) void node_count_kernel(const unsigned* __restrict__ keys,
                                                         const int* __restrict__ bcnt,
                                                         int* __restrict__ cnt,
                                                         int* __restrict__ bsum) {
    __shared__ int lc[256], rs[256];
    int tid = threadIdx.x, b = blockIdx.x;
    lc[tid] = 0;
    __syncthreads();
    int beg = b * CAPB, end = beg + bcnt[b];
    for (int p = beg + tid; p < end; p += 256)
        atomicAdd(&lc[(keys[p] >> 16) & 255], 1);
    __syncthreads();
    int node = b * 256 + tid;
    int c = (node < N_NODES) ? lc[tid] : 0;
    if (node < N_NODES) cnt[node] = c;
    rs[tid] = (c + 15) & ~15;
    __syncthreads();
    for (int off = 128; off > 0; off >>= 1) {
        if (tid < off) rs[tid] += rs[tid + off];
        __syncthreads();
    }
    if (tid == 0) bsum[b] = rs[0];
}

// exclusive scan of padded bucket sums -> bbase; writes row_start[N_NODES]
__global__ void pscan_kernel(const int* __restrict__ bsum, int* __restrict__ bbase,
                             int* __restrict__ row_start) {
    __shared__ int a[256];
    int tid = threadIdx.x;
    int v = (tid < NB) ? bsum[tid] : 0;
    a[tid] = v;
    __syncthreads();
    for (int off = 1; off < 256; off <<= 1) {
        int t = (tid >= off) ? a[tid - off] : 0;
        __syncthreads();
        a[tid] += t;
        __syncthreads();
    }
    int excl = a[tid] - v;
    if (tid < NB) bbase[tid] = excl;
    if (tid == NB - 1) row_start[N_NODES] = excl + v;
}

// ==================== pass 2: local scan -> row_start, block-local scatter + pad fill ============
__global__ __launch_bounds__(256) void pass2_kernel(const unsigned* __restrict__ keys,
                                                    const int* __restrict__ bcnt,
                                                    const int* __restrict__ cnt,
                                                    const int* __restrict__ bbase,
                                                    int* __restrict__ row_start,
                                                    unsigned short* __restrict__ sorted_src) {
    __shared__ int loc[256], rs[256], cur[256];
    int tid = threadIdx.x, b = blockIdx.x;
    int node = b * 256 + tid;
    int c = (node < N_NODES) ? cnt[node] : 0;
    int pc = (c + 15) & ~15;
    loc[tid] = pc;
    cur[tid] = 0;
    __syncthreads();
    for (int off = 1; off < 256; off <<= 1) {
        int t = (tid >= off) ? loc[tid - off] : 0;
        __syncthreads();
        loc[tid] += t;
        __syncthreads();
    }
    int myrs = bbase[b] + loc[tid] - pc;  // exclusive
    rs[tid] = myrs;
    if (node < N_NODES) row_start[node] = myrs;
    __syncthreads();
    int beg = b * CAPB, end = beg + bcnt[b];
    for (int p = beg + tid; p < end; p += 256) {
        unsigned k = keys[p];
        int lidx = (k >> 16) & 255;
        int r = atomicAdd(&cur[lidx], 1);
        sorted_src[rs[lidx] + r] = (unsigned short)(k & 0xFFFFu);
    }
    __syncthreads();
    if (node < N_NODES) {
        int deg = cur[tid];
        if (deg > 0) {
            unsigned short s0 = sorted_src[myrs];
            for (int p = myrs + deg; p < myrs + pc; p++) sorted_src[p] = s0;  // max idempotent
        }
    }
}

// ============ fc0 via MFMA: h0[16-node tile] = x @ fc0_w + b (f16 out) + BN stats ============
__global__ __launch_bounds__(256, 3) void fc0_mfma_kernel(const float* __restrict__ x,
                                                          const float* __restrict__ w,
                                                          const float* __restrict__ b,
                                                          unsigned short* __restrict__ h0,
                                                          float* __restrict__ bns) {
    __shared__ float bl1[4][64], bl2[4][64];
    int tid = threadIdx.x, lane = tid & 63, wid = tid >> 6;
    int q = lane >> 4, cl = lane & 15, kq = q * 8;

    Uh wf[4][4];
#pragma unroll
    for (int kh = 0; kh < 4; kh++)
#pragma unroll
        for (int cb = 0; cb < 4; cb++)
#pragma unroll
            for (int j = 0; j < 4; j++) {
                int k0 = kh * 32 + kq + 2 * j;
                int col = cb * 16 + cl;
                wf[kh][cb].h[j] = pk2(w[k0 * 64 + col], w[(k0 + 1) * 64 + col]);
            }
    float bv[4];
#pragma unroll
    for (int cb = 0; cb < 4; cb++) bv[cb] = b[cb * 16 + cl];
    float s1[4] = {0, 0, 0, 0}, s2[4] = {0, 0, 0, 0};

    for (int t = blockIdx.x * 4 + wid; t < N_TILES; t += gridDim.x * 4) {
        int nb = t * 16;
        floatx4 acc[4] = {{0,0,0,0},{0,0,0,0},{0,0,0,0},{0,0,0,0}};
#pragma unroll
        for (int kh = 0; kh < 4; kh++) {
            const float* xr = x + (size_t)(nb + cl) * F_IN + kh * 32 + kq;
            floatx4 xa = *(const floatx4*)xr;
            floatx4 xb = *(const floatx4*)(xr + 4);
            Uh xf;
            xf.h[0] = pk2(xa.x, xa.y); xf.h[1] = pk2(xa.z, xa.w);
            xf.h[2] = pk2(xb.x, xb.y); xf.h[3] = pk2(xb.z, xb.w);
#pragma unroll
            for (int cb = 0; cb < 4; cb++)
                acc[cb] = __builtin_amdgcn_mfma_f32_16x16x32_f16(xf.h8, wf[kh][cb].h8, acc[cb], 0, 0, 0);
        }
#pragma unroll
        for (int cb = 0; cb < 4; cb++)
#pragma unroll
            for (int r = 0; r < 4; r++) {
                float v = acc[cb][r] + bv[cb];            // node = nb+q*4+r, col = cb*16+cl
                h0[(size_t)(nb + q * 4 + r) * 64 + cb * 16 + cl] = f2h(v);
                s1[cb] += v; s2[cb] += v * v;
            }
    }
#pragma unroll
    for (int cb = 0; cb < 4; cb++) {
        s1[cb] += __shfl_xor(s1[cb], 16); s1[cb] += __shfl_xor(s1[cb], 32);
        s2[cb] += __shfl_xor(s2[cb], 16); s2[cb] += __shfl_xor(s2[cb], 32);
    }
    if (lane < 16) {
#pragma unroll
        for (int cb = 0; cb < 4; cb++) { bl1[wid][cb * 16 + lane] = s1[cb]; bl2[wid][cb * 16 + lane] = s2[cb]; }
    }
    __syncthreads();
    if (tid < 64) {
        float a  = bl1[0][tid] + bl1[1][tid] + bl1[2][tid] + bl1[3][tid];
        float c2 = bl2[0][tid] + bl2[1][tid] + bl2[2][tid] + bl2[3][tid];
        int sl = blockIdx.x & (NSLICE - 1);
        atomicAdd(&bns[sl * 128 + tid], a);
        atomicAdd(&bns[sl * 128 + 64 + tid], c2);
    }
}

// ============ ab via MFMA: A = bn(h)@WA + cA, B = bn(h)@WB + cB (both f16) ============
__global__ __launch_bounds__(256, 4) void ab_mfma_kernel(const unsigned short* __restrict__ h,
                                                         const float* __restrict__ bns,
                                                         const float* __restrict__ g,
                                                         const float* __restrict__ bb,
                                                         const float* __restrict__ w1,
                                                         const float* __restrict__ b1,
                                                         unsigned short* __restrict__ A,
                                                         unsigned short* __restrict__ Bb) {
    __shared__ float scale[64], shift[64], cab[128];
    int tid = threadIdx.x, lane = tid & 63, wid = tid >> 6;
    int q = lane >> 4, cl = lane & 15, kq = q * 8;

    if (tid < 64) {
        float s1v = 0.f, s2v = 0.f;
#pragma unroll
        for (int s = 0; s < NSLICE; s++) { s1v += bns[s * 128 + tid]; s2v += bns[s * 128 + 64 + tid]; }
        float mu  = s1v * (1.0f / N_NODES);
        float var = s2v * (1.0f / N_NODES) - mu * mu;
        float sc  = g[tid] * rsqrtf(var + EPS);
        scale[tid] = sc;
        shift[tid] = bb[tid] - mu * sc;
    }
    __syncthreads();
    if (tid < 128) {
        int j = tid & 63;
        float acc = (tid < 64) ? b1[j] : 0.f;
        for (int k = 0; k < 64; k++) {
            float wa_ = w1[k * EF + j], wb_ = w1[(64 + k) * EF + j];
            acc = fmaf(shift[k], (tid < 64) ? (wa_ - wb_) : wb_, acc);
        }
        cab[tid] = acc;
    }
    Uh wa[2][4], wb[2][4];
#pragma unroll
    for (int kh = 0; kh < 2; kh++)
#pragma unroll
        for (int cb = 0; cb < 4; cb++)
#pragma unroll
            for (int j = 0; j < 4; j++) {
                int k0 = kh * 32 + kq + 2 * j;
                int col = cb * 16 + cl;
                float sa = scale[k0], sb = scale[k0 + 1];
                float a0 = w1[k0 * EF + col], b0 = w1[(64 + k0) * EF + col];
                float a1 = w1[(k0 + 1) * EF + col], b1v = w1[(64 + k0 + 1) * EF + col];
                wa[kh][cb].h[j] = pk2(sa * (a0 - b0), sb * (a1 - b1v));
                wb[kh][cb].h[j] = pk2(sa * b0, sb * b1v);
            }
    __syncthreads();
    float cav[4], cbv[4];
#pragma unroll
    for (int cb = 0; cb < 4; cb++) { cav[cb] = cab[cb * 16 + cl]; cbv[cb] = cab[64 + cb * 16 + cl]; }

    for (int t = blockIdx.x * 4 + wid; t < N_TILES; t += gridDim.x * 4) {
        int nb = t * 16;
        const unsigned short* hrow = h + (size_t)(nb + cl) * 64 + kq;
        Uh h0f, h1f;
        h0f.v = *(const uintx4*)hrow;
        h1f.v = *(const uintx4*)(hrow + 32);
        floatx4 accA[4] = {{0,0,0,0},{0,0,0,0},{0,0,0,0},{0,0,0,0}};
        floatx4 accB[4] = {{0,0,0,0},{0,0,0,0},{0,0,0,0},{0,0,0,0}};
#pragma unroll
        for (int cb = 0; cb < 4; cb++) {
            accA[cb] = __builtin_amdgcn_mfma_f32_16x16x32_f16(h0f.h8, wa[0][cb].h8, accA[cb], 0, 0, 0);
            accB[cb] = __builtin_amdgcn_mfma_f32_16x16x32_f16(h0f.h8, wb[0][cb].h8, accB[cb], 0, 0, 0);
            accA[cb] = __builtin_amdgcn_mfma_f32_16x16x32_f16(h1f.h8, wa[1][cb].h8, accA[cb], 0, 0, 0);
            accB[cb] = __builtin_amdgcn_mfma_f32_16x16x32_f16(h1f.h8, wb[1][cb].h8, accB[cb], 0, 0, 0);
        }
#pragma unroll
        for (int cb = 0; cb < 4; cb++)
#pragma unroll
            for (int r = 0; r < 4; r++) {
                size_t o = (size_t)(nb + q * 4 + r) * 64 + cb * 16 + cl;
                A[o]  = f2h(accA[cb][r] + cav[cb]);
                Bb[o] = f2h(accB[cb][r] + cbv[cb]);
            }
    }
}

// ============ EdgeConv via f16 MFMA: 2-node interleave over padded+filled CSR ============
// Plain __launch_bounds__(256): est ~110 VGPR, no cap-induced spill (R7 lesson).
__global__ __launch_bounds__(256) void edge_mfma_kernel(
        const unsigned short* __restrict__ A, const unsigned short* __restrict__ Bb,
        const int* __restrict__ row_start, const unsigned short* __restrict__ sorted_src,
        const float* __restrict__ w2, const float* __restrict__ b2,
        unsigned short* __restrict__ catp, float* __restrict__ bnsNext) {
    __shared__ float r1s[4][64], r2s[4][64];
    int tid = threadIdx.x, lane = tid & 63, wid = tid >> 6;
    int kq = (lane >> 4) * 8;
    int cl = lane & 15;

    Uh bfr[2][4];
#pragma unroll
    for (int kh = 0; kh < 2; kh++)
#pragma unroll
        for (int cb = 0; cb < 4; cb++)
#pragma unroll
            for (int j = 0; j < 4; j++) {
                _Float16 w0 = (_Float16)w2[(kh * 32 + kq + 2 * j) * 64 + cb * 16 + cl];
                _Float16 w1 = (_Float16)w2[(kh * 32 + kq + 2 * j + 1) * 64 + cb * 16 + cl];
                bfr[kh][cb].h[j] = half2v{w0, w1};
            }
    float b2j = b2[lane];
    float s1 = 0.f, s2 = 0.f;
    const half2v zeroh = {(_Float16)0.f, (_Float16)0.f};

    auto gather = [&](int p, uintx4& u0, uintx4& u1) {
        int srcm = sorted_src[p + cl];
        const unsigned short* brow = Bb + (size_t)srcm * 64 + kq;
        u0 = *(const uintx4*)(brow);
        u1 = *(const uintx4*)(brow + 32);
    };

    for (int nb = blockIdx.x * 8 + wid * 2; nb < N_NODES; nb += gridDim.x * 8) {
        int n0 = nb, n1 = nb + 1;                    // N_NODES even -> n1 always valid
        int rs0 = row_start[n0], e0p = row_start[n0 + 1];
        int rs1 = e0p,           e1p = row_start[n1 + 1];
        const unsigned short* ar0 = A + (size_t)n0 * 64 + kq;
        const unsigned short* ar1 = A + (size_t)n1 * 64 + kq;
        Uh a00, a01, a10, a11;
        a00.v = *(const uintx4*)ar0; a01.v = *(const uintx4*)(ar0 + 32);
        a10.v = *(const uintx4*)ar1; a11.v = *(const uintx4*)(ar1 + 32);
        floatx4 rm0[4], rm1[4];
#pragma unroll
        for (int i = 0; i < 4; i++) {
            rm0[i] = floatx4{-INFINITY, -INFINITY, -INFINITY, -INFINITY};
            rm1[i] = rm0[i];
        }

        auto tile = [&](Uh& aa0, Uh& aa1, floatx4 (&rm)[4], uintx4 u0, uintx4 u1) {
            Uh b0u, b1u, f0, f1;
            b0u.v = u0; b1u.v = u1;
#pragma unroll
            for (int j = 0; j < 4; j++) {            // v_pk_add_f16 + v_pk_max_f16
                f0.h[j] = __builtin_elementwise_max(aa0.h[j] + b0u.h[j], zeroh);
                f1.h[j] = __builtin_elementwise_max(aa1.h[j] + b1u.h[j], zeroh);
            }
#pragma unroll
            for (int cb = 0; cb < 4; cb++) {
                floatx4 acc = {0.f, 0.f, 0.f, 0.f};
                acc = __builtin_amdgcn_mfma_f32_16x16x32_f16(f0.h8, bfr[0][cb].h8, acc, 0, 0, 0);
                acc = __builtin_amdgcn_mfma_f32_16x16x32_f16(f1.h8, bfr[1][cb].h8, acc, 0, 0, 0);
                rm[cb] = __builtin_elementwise_max(rm[cb], acc);
            }
        };

        int p0 = rs0, p1 = rs1;
        while (p0 < e0p || p1 < e1p) {               // wave-uniform conditions
            uintx4 x0, x1, y0, y1;
            bool d0 = p0 < e0p, d1 = p1 < e1p;
            if (d0) gather(p0, x0, x1);
            if (d1) gather(p1, y0, y1);
            if (d0) { tile(a00, a01, rm0, x0, x1); p0 += 16; }
            if (d1) { tile(a10, a11, rm1, y0, y1); p1 += 16; }
        }

        auto finish = [&](floatx4 (&rm)[4], int n) {
            float v0 = fmaxf(fmaxf(rm[0].x, rm[0].y), fmaxf(rm[0].z, rm[0].w));
            float v1 = fmaxf(fmaxf(rm[1].x, rm[1].y), fmaxf(rm[1].z, rm[1].w));
            float v2 = fmaxf(fmaxf(rm[2].x, rm[2].y), fmaxf(rm[2].z, rm[2].w));
            float v3 = fmaxf(fmaxf(rm[3].x, rm[3].y), fmaxf(rm[3].z, rm[3].w));
            v0 = fmaxf(v0, __shfl_xor(v0, 16)); v0 = fmaxf(v0, __shfl_xor(v0, 32));
            v1 = fmaxf(v1, __shfl_xor(v1, 16)); v1 = fmaxf(v1, __shfl_xor(v1, 32));
            v2 = fmaxf(v2, __shfl_xor(v2, 16)); v2 = fmaxf(v2, __shfl_xor(v2, 32));
            v3 = fmaxf(v3, __shfl_xor(v3, 16)); v3 = fmaxf(v3, __shfl_xor(v3, 32));
            float vs = (lane & 32) ? ((lane & 16) ? v3 : v2) : ((lane & 16) ? v1 : v0);
            float v = fmaxf(vs + b2j, 0.f);          // -inf (empty node) -> 0
            catp[(size_t)n * 64 + lane] = f2h(v);
            s1 += v; s2 += v * v;
        };
        finish(rm0, n0);
        finish(rm1, n1);
    }

    if (bnsNext) {
        r1s[wid][lane] = s1; r2s[wid][lane] = s2;
        __syncthreads();
        if (tid < 64) {
            float a  = r1s[0][tid] + r1s[1][tid] + r1s[2][tid] + r1s[3][tid];
            float c2 = r2s[0][tid] + r2s[1][tid] + r2s[2][tid] + r2s[3][tid];
            int sl = blockIdx.x & (NSLICE - 1);
            atomicAdd(&bnsNext[sl * 128 + tid], a);
            atomicAdd(&bnsNext[sl * 128 + 64 + tid], c2);
        }
    }
}

// ============================ fused graph mean pool + MLP head + log_softmax ============================
__global__ __launch_bounds__(192) void poolhead_kernel(const unsigned short* __restrict__ cat0,
                                                       const unsigned short* __restrict__ cat1,
                                                       const unsigned short* __restrict__ cat2,
                                                       const int* __restrict__ batch,
                                                       const float* __restrict__ fc1w,
                                                       const float* __restrict__ fc1b,
                                                       const float* __restrict__ fc2w,
                                                       const float* __restrict__ fc2b,
                                                       float* __restrict__ out) {
    __shared__ int se[2];
    __shared__ float p[192];
    __shared__ float hid[128];
    __shared__ float z[10];
    __shared__ float lse;
    int g = blockIdx.x, tid = threadIdx.x;  // 192 threads
    if (tid < 2) {
        int target = g + tid;
        int lo = 0, hi = N_NODES;
        while (lo < hi) { int mid = (lo + hi) >> 1; if (batch[mid] < target) lo = mid + 1; else hi = mid; }
        se[tid] = lo;
    }
    __syncthreads();
    int s = se[0], e = se[1];
    const unsigned short* plane = (tid < 64) ? cat0 : ((tid < 128) ? cat1 : cat2);
    int col = tid & 63;
    float a0 = 0.f, a1 = 0.f, a2 = 0.f, a3 = 0.f;   // 4-way ILP in the pooling loop
    int r = s;
    for (; r + 4 <= e; r += 4) {
        a0 += h2f(plane[(size_t)(r + 0) * 64 + col]);
        a1 += h2f(plane[(size_t)(r + 1) * 64 + col]);
        a2 += h2f(plane[(size_t)(r + 2) * 64 + col]);
        a3 += h2f(plane[(size_t)(r + 3) * 64 + col]);
    }
    for (; r < e; r++) a0 += h2f(plane[(size_t)r * 64 + col]);
    float acc = (a0 + a1) + (a2 + a3);
    float denom = (e > s) ? (float)(e - s) : 1.0f;
    p[tid] = acc / denom;
    __syncthreads();
    if (tid < MLP_DIM) {
        float a = fc1b[tid];
        for (int k = 0; k < 192; k++) a = fmaf(p[k], fc1w[k * 128 + tid], a);
        hid[tid] = fmaxf(a, 0.f);
    }
    __syncthreads();
    if (tid < N_CLASSES) {
        float a = fc2b[tid];
        for (int k = 0; k < 128; k++) a = fmaf(hid[k], fc2w[k * 10 + tid], a);
        z[tid] = a;
    }
    __syncthreads();
    if (tid == 0) {
        float m = z[0];
        for (int i = 1; i < 10; i++) m = fmaxf(m, z[i]);
        float sm = 0.f;
        for (int i = 0; i < 10; i++) sm += expf(z[i] - m);
        lse = m + logf(sm);
    }
    __syncthreads();
    if (tid < N_CLASSES) out[g * 10 + tid] = z[tid] - lse;
}

// ============================ launch ============================
extern "C" void kernel_launch(void* const* d_in, const int* in_sizes, int n_in,
                              void* d_out, int out_size, void* d_ws, size_t ws_size,
                              hipStream_t stream) {
    (void)in_sizes; (void)n_in; (void)out_size; (void)ws_size;
    const float* x    = (const float*)d_in[0];
    const int*   ei   = (const int*)d_in[1];
    const int*   batch= (const int*)d_in[2];
    const float* fc0w = (const float*)d_in[3];
    const float* fc0b = (const float*)d_in[4];
    const float* fc1w = (const float*)d_in[5];
    const float* fc1b = (const float*)d_in[6];
    const float* fc2w = (const float*)d_in[7];
    const float* fc2b = (const float*)d_in[8];
    const int* src = ei;
    const int* dst = ei + N_EDGES;
    float* out = (float*)d_out;

    char* w = (char*)d_ws;
    size_t off = 0;
    auto alloc = [&](size_t bytes) -> void* {
        void* p = w + off;
        off = (off + bytes + 255) & ~(size_t)255;
        return p;
    };
    const size_t MAX_PAD_EDGES = (size_t)N_EDGES + 16 * (size_t)N_NODES;

    // zeroed-every-launch block: gcur[NB] | bns[3][NSLICE][128]
    char* zbase = (char*)alloc(1024 + 3 * NSLICE * 128 * 4);
    int*   gcur   = (int*)zbase;                     // NB ints (bucket cursors = final counts)
    float* bnsAll = (float*)(zbase + 1024);          // 3 * NSLICE * 128 floats
    const size_t ZBYTES = 1024 + 3 * NSLICE * 128 * 4;

    unsigned short* cat0 = (unsigned short*)alloc((size_t)N_NODES * 64 * 2);  // 6.4 MB/plane (f16)
    unsigned short* cat1 = (unsigned short*)alloc((size_t)N_NODES * 64 * 2);
    unsigned short* cat2 = (unsigned short*)alloc((size_t)N_NODES * 64 * 2);
    unsigned short* h0   = (unsigned short*)alloc((size_t)N_NODES * 64 * 2);
    unsigned short* Ae   = (unsigned short*)alloc((size_t)N_NODES * 64 * 2);
    unsigned short* Be   = (unsigned short*)alloc((size_t)N_NODES * 64 * 2);
    unsigned* keys = (unsigned*)alloc((size_t)NB * CAPB * 4);    // 12.85 MB
    unsigned short* sorted_src = (unsigned short*)alloc(MAX_PAD_EDGES * 2);  // 4.8 MB
    int*   cnt     = (int*)alloc((size_t)N_NODES * 4);
    int*   row_start = (int*)alloc((size_t)(N_NODES + 1) * 4);
    int*   bsum    = (int*)alloc(NB * 4);
    int*   bbase   = (int*)alloc(NB * 4);

    (void)hipMemsetAsync(zbase, 0, ZBYTES, stream);

    // --- two-level counting sort (R10 chain — no random global atomics) ---
    pass1_kernel<<<(N_EDGES + CHUNK - 1) / CHUNK, 256, 0, stream>>>(src, dst, gcur, keys);
    node_count_kernel<<<NB, 256, 0, stream>>>(keys, gcur, cnt, bsum);
    pscan_kernel<<<1, 256, 0, stream>>>(bsum, bbase, row_start);
    pass2_kernel<<<NB, 256, 0, stream>>>(keys, gcur, cnt, bbase, row_start, sorted_src);

    fc0_mfma_kernel<<<782, 256, 0, stream>>>(x, fc0w, fc0b, h0, bnsAll);

    unsigned short* planes[3] = {cat0, cat1, cat2};
    for (int blk = 0; blk < 3; blk++) {
        const float* g  = (const float*)d_in[9 + 6 * blk];
        const float* bb = (const float*)d_in[10 + 6 * blk];
        const float* w1 = (const float*)d_in[11 + 6 * blk];
        const float* b1 = (const float*)d_in[12 + 6 * blk];
        const float* w2 = (const float*)d_in[13 + 6 * blk];
        const float* b2 = (const float*)d_in[14 + 6 * blk];
        const unsigned short* hsrc = (blk == 0) ? h0 : planes[blk - 1];

        ab_mfma_kernel<<<782, 256, 0, stream>>>(hsrc, bnsAll + blk * NSLICE * 128,
                                                g, bb, w1, b1, Ae, Be);
        edge_mfma_kernel<<<2048, 256, 0, stream>>>(
            Ae, Be, row_start, sorted_src, w2, b2, planes[blk],
            (blk < 2) ? (bnsAll + (blk + 1) * NSLICE * 128) : nullptr);
    }

    poolhead_kernel<<<N_GRAPHS, 192, 0, stream>>>(cat0, cat1, cat2, batch,
                                                  fc1w, fc1b, fc2w, fc2b, out);
}

// Round 13
// 428.563 us; speedup vs baseline: 1.2733x; 1.0931x over previous
//
#include <hip/hip_runtime.h>
#include <math.h>

#define N_NODES 50000
#define N_TILES 3125      // N_NODES / 16 exactly
#define N_EDGES 1600000
#define F_IN 128
#define C 64
#define EF 64
#define N_GRAPHS 512
#define MLP_DIM 128
#define N_CLASSES 10
#define EPS 1e-5f
#define NB 196            // coarse buckets: dst>>8, 256 nodes each
#define CAPB 16384        // fixed bucket capacity (mean 8192, std ~90 -> safe)
#define CHUNK 4096        // edges per pass-1 block
#define NSLICE 8          // bn-stat atomic slices

typedef __attribute__((ext_vector_type(8))) _Float16 half8;
typedef __attribute__((ext_vector_type(2))) _Float16 half2v;
typedef __attribute__((ext_vector_type(4))) float floatx4;
typedef __attribute__((ext_vector_type(4))) unsigned uintx4;

union Uh { uintx4 v; half2v h[4]; half8 h8; };

__device__ __forceinline__ unsigned short f2h(float a) {
    union { _Float16 f; unsigned short u; } c;
    c.f = (_Float16)a;   // RNE
    return c.u;
}
__device__ __forceinline__ float h2f(unsigned short u) {
    union { unsigned short u; _Float16 f; } c;
    c.u = u;
    return (float)c.f;
}
__device__ __forceinline__ half2v pk2(float a, float b) {
    auto t = __builtin_amdgcn_cvt_pkrtz(a, b);   // __fp16 vec2 -> bit-cast (R6 lesson)
    union { decltype(t) i; half2v o; } c;
    c.i = t;
    return c.o;
}

// ==================== sort pass 1: bin edges into fixed-capacity buckets ====================
// NO per-node global atomics here — R11: 1.6M random atomicAdds cost 57 MB cross-XCD writeback.
__global__ __launch_bounds__(256) void pass1_kernel(const int* __restrict__ src,
                                                    const int* __restrict__ dst,
                                                    int* __restrict__ gcur,
                                                    unsigned* __restrict__ keys) {
    __shared__ int lcnt[NB], lbase[NB], lcnt2[NB];
    int tid = threadIdx.x;
    int e0 = blockIdx.x * CHUNK;
    unsigned k[CHUNK / 256];
    int bk[CHUNK / 256];
    for (int i = tid; i < NB; i += 256) lcnt[i] = 0;
    __syncthreads();
#pragma unroll
    for (int i = 0; i < CHUNK / 256; i++) {
        int e = e0 + i * 256 + tid;
        if (e < N_EDGES) {
            int d = dst[e];
            k[i] = ((unsigned)d << 16) | (unsigned)src[e];
            bk[i] = d >> 8;
            atomicAdd(&lcnt[bk[i]], 1);
        } else bk[i] = -1;
    }
    __syncthreads();
    for (int i = tid; i < NB; i += 256) {
        int c = lcnt[i];
        lbase[i] = c ? atomicAdd(&gcur[i], c) : 0;
        lcnt2[i] = 0;
    }
    __syncthreads();
#pragma unroll
    for (int i = 0; i < CHUNK / 256; i++) {
        if (bk[i] >= 0) {
            int r = atomicAdd(&lcnt2[bk[i]], 1);
            keys[(size_t)bk[i] * CAPB + lbase[bk[i]] + r] = k[i];
        }
    }
}

// ============ per-node degree: 2 blocks/bucket (392 blocks), LDS hist + coalesced atomics ============
__global__ __launch_bounds__(256) void node_count_kernel(const unsigned* __restrict__ keys,
                                                         const int* __restrict__ bcnt,
                                                         int* __restrict__ cnt) {
    __shared__ int lc[256];
    int tid = threadIdx.x;
    int b = blockIdx.x >> 1, half = blockIdx.x & 1;
    lc[tid] = 0;
    __syncthreads();
    int nk = bcnt[b];
    int chunk = (nk + 1) >> 1;
    int beg = half * chunk;
    int end = beg + chunk; if (end > nk) end = nk;
    const unsigned* kb = keys + (size_t)b * CAPB;
    for (int p = beg + tid; p < end; p += 256)
        atomicAdd(&lc[(kb[p] >> 16) & 255], 1);
    __syncthreads();
    int node = b * 256 + tid;
    if (node < N_NODES && lc[tid]) atomicAdd(&cnt[node], lc[tid]);  // coalesced, 2-way
}

// ===== pscan: per-bucket padded sums straight from cnt, exclusive scan -> bbase =====
__global__ void pscan_kernel(const int* __restrict__ cnt, int* __restrict__ bbase,
                             int* __restrict__ row_start) {
    __shared__ int a[256];
    int tid = threadIdx.x;
    int sum = 0;
    if (tid < NB) {
        int base = tid * 256;
        for (int i = 0; i < 256; i++) {
            int node = base + i;
            if (node < N_NODES) sum += (cnt[node] + 15) & ~15;
        }
    }
    a[tid] = sum;
    __syncthreads();
    for (int off = 1; off < 256; off <<= 1) {
        int t = (tid >= off) ? a[tid - off] : 0;
        __syncthreads();
        a[tid] += t;
        __syncthreads();
    }
    int excl = a[tid] - sum;
    if (tid < NB) bbase[tid] = excl;
    if (tid == NB - 1) row_start[N_NODES] = excl + sum;
}

// ==================== pass 2: local scan -> row_start, block-local scatter + pad fill ============
__global__ __launch_bounds__(256) void pass2_kernel(const unsigned* __restrict__ keys,
                                                    const int* __restrict__ bcnt,
                                                    const int* __restrict__ cnt,
                                                    const int* __restrict__ bbase,
                                                    int* __restrict__ row_start,
                                                    unsigned short* __restrict__ sorted_src) {
    __shared__ int loc[256], rs[256], cur[256];
    int tid = threadIdx.x, b = blockIdx.x;
    int node = b * 256 + tid;
    int c = (node < N_NODES) ? cnt[node] : 0;
    int pc = (c + 15) & ~15;
    loc[tid] = pc;
    cur[tid] = 0;
    __syncthreads();
    for (int off = 1; off < 256; off <<= 1) {
        int t = (tid >= off) ? loc[tid - off] : 0;
        __syncthreads();
        loc[tid] += t;
        __syncthreads();
    }
    int myrs = bbase[b] + loc[tid] - pc;  // exclusive
    rs[tid] = myrs;
    if (node < N_NODES) row_start[node] = myrs;
    __syncthreads();
    int beg = b * CAPB, end = beg + bcnt[b];
    for (int p = beg + tid; p < end; p += 256) {
        unsigned k = keys[p];
        int lidx = (k >> 16) & 255;
        int r = atomicAdd(&cur[lidx], 1);
        sorted_src[rs[lidx] + r] = (unsigned short)(k & 0xFFFFu);
    }
    __syncthreads();
    if (node < N_NODES) {
        int deg = cur[tid];
        if (deg > 0) {
            unsigned short s0 = sorted_src[myrs];
            for (int p = myrs + deg; p < myrs + pc; p++) sorted_src[p] = s0;  // max idempotent
        }
    }
}

// ============ fc0 via MFMA: h0[16-node tile] = x @ fc0_w + b (f16 out) + BN stats ============
__global__ __launch_bounds__(256, 3) void fc0_mfma_kernel(const float* __restrict__ x,
                                                          const float* __restrict__ w,
                                                          const float* __restrict__ b,
                                                          unsigned short* __restrict__ h0,
                                                          float* __restrict__ bns) {
    __shared__ float bl1[4][64], bl2[4][64];
    int tid = threadIdx.x, lane = tid & 63, wid = tid >> 6;
    int q = lane >> 4, cl = lane & 15, kq = q * 8;

    Uh wf[4][4];
#pragma unroll
    for (int kh = 0; kh < 4; kh++)
#pragma unroll
        for (int cb = 0; cb < 4; cb++)
#pragma unroll
            for (int j = 0; j < 4; j++) {
                int k0 = kh * 32 + kq + 2 * j;
                int col = cb * 16 + cl;
                wf[kh][cb].h[j] = pk2(w[k0 * 64 + col], w[(k0 + 1) * 64 + col]);
            }
    float bv[4];
#pragma unroll
    for (int cb = 0; cb < 4; cb++) bv[cb] = b[cb * 16 + cl];
    float s1[4] = {0, 0, 0, 0}, s2[4] = {0, 0, 0, 0};

    for (int t = blockIdx.x * 4 + wid; t < N_TILES; t += gridDim.x * 4) {
        int nb = t * 16;
        floatx4 acc[4] = {{0,0,0,0},{0,0,0,0},{0,0,0,0},{0,0,0,0}};
#pragma unroll
        for (int kh = 0; kh < 4; kh++) {
            const float* xr = x + (size_t)(nb + cl) * F_IN + kh * 32 + kq;
            floatx4 xa = *(const floatx4*)xr;
            floatx4 xb = *(const floatx4*)(xr + 4);
            Uh xf;
            xf.h[0] = pk2(xa.x, xa.y); xf.h[1] = pk2(xa.z, xa.w);
            xf.h[2] = pk2(xb.x, xb.y); xf.h[3] = pk2(xb.z, xb.w);
#pragma unroll
            for (int cb = 0; cb < 4; cb++)
                acc[cb] = __builtin_amdgcn_mfma_f32_16x16x32_f16(xf.h8, wf[kh][cb].h8, acc[cb], 0, 0, 0);
        }
#pragma unroll
        for (int cb = 0; cb < 4; cb++)
#pragma unroll
            for (int r = 0; r < 4; r++) {
                float v = acc[cb][r] + bv[cb];            // node = nb+q*4+r, col = cb*16+cl
                h0[(size_t)(nb + q * 4 + r) * 64 + cb * 16 + cl] = f2h(v);
                s1[cb] += v; s2[cb] += v * v;
            }
    }
#pragma unroll
    for (int cb = 0; cb < 4; cb++) {
        s1[cb] += __shfl_xor(s1[cb], 16); s1[cb] += __shfl_xor(s1[cb], 32);
        s2[cb] += __shfl_xor(s2[cb], 16); s2[cb] += __shfl_xor(s2[cb], 32);
    }
    if (lane < 16) {
#pragma unroll
        for (int cb = 0; cb < 4; cb++) { bl1[wid][cb * 16 + lane] = s1[cb]; bl2[wid][cb * 16 + lane] = s2[cb]; }
    }
    __syncthreads();
    if (tid < 64) {
        float a  = bl1[0][tid] + bl1[1][tid] + bl1[2][tid] + bl1[3][tid];
        float c2 = bl2[0][tid] + bl2[1][tid] + bl2[2][tid] + bl2[3][tid];
        int sl = blockIdx.x & (NSLICE - 1);
        atomicAdd(&bns[sl * 128 + tid], a);
        atomicAdd(&bns[sl * 128 + 64 + tid], c2);
    }
}

// ============ ab via MFMA: A = bn(h)@WA + cA, B = bn(h)@WB + cB (both f16) ============
__global__ __launch_bounds__(256, 4) void ab_mfma_kernel(const unsigned short* __restrict__ h,
                                                         const float* __restrict__ bns,
                                                         const float* __restrict__ g,
                                                         const float* __restrict__ bb,
                                                         const float* __restrict__ w1,
                                                         const float* __restrict__ b1,
                                                         unsigned short* __restrict__ A,
                                                         unsigned short* __restrict__ Bb) {
    __shared__ float scale[64], shift[64], cab[128];
    int tid = threadIdx.x, lane = tid & 63, wid = tid >> 6;
    int q = lane >> 4, cl = lane & 15, kq = q * 8;

    if (tid < 64) {
        float s1v = 0.f, s2v = 0.f;
#pragma unroll
        for (int s = 0; s < NSLICE; s++) { s1v += bns[s * 128 + tid]; s2v += bns[s * 128 + 64 + tid]; }
        float mu  = s1v * (1.0f / N_NODES);
        float var = s2v * (1.0f / N_NODES) - mu * mu;
        float sc  = g[tid] * rsqrtf(var + EPS);
        scale[tid] = sc;
        shift[tid] = bb[tid] - mu * sc;
    }
    __syncthreads();
    if (tid < 128) {
        int j = tid & 63;
        float acc = (tid < 64) ? b1[j] : 0.f;
        for (int k = 0; k < 64; k++) {
            float wa_ = w1[k * EF + j], wb_ = w1[(64 + k) * EF + j];
            acc = fmaf(shift[k], (tid < 64) ? (wa_ - wb_) : wb_, acc);
        }
        cab[tid] = acc;
    }
    Uh wa[2][4], wb[2][4];
#pragma unroll
    for (int kh = 0; kh < 2; kh++)
#pragma unroll
        for (int cb = 0; cb < 4; cb++)
#pragma unroll
            for (int j = 0; j < 4; j++) {
                int k0 = kh * 32 + kq + 2 * j;
                int col = cb * 16 + cl;
                float sa = scale[k0], sb = scale[k0 + 1];
                float a0 = w1[k0 * EF + col], b0 = w1[(64 + k0) * EF + col];
                float a1 = w1[(k0 + 1) * EF + col], b1v = w1[(64 + k0 + 1) * EF + col];
                wa[kh][cb].h[j] = pk2(sa * (a0 - b0), sb * (a1 - b1v));
                wb[kh][cb].h[j] = pk2(sa * b0, sb * b1v);
            }
    __syncthreads();
    float cav[4], cbv[4];
#pragma unroll
    for (int cb = 0; cb < 4; cb++) { cav[cb] = cab[cb * 16 + cl]; cbv[cb] = cab[64 + cb * 16 + cl]; }

    for (int t = blockIdx.x * 4 + wid; t < N_TILES; t += gridDim.x * 4) {
        int nb = t * 16;
        const unsigned short* hrow = h + (size_t)(nb + cl) * 64 + kq;
        Uh h0f, h1f;
        h0f.v = *(const uintx4*)hrow;
        h1f.v = *(const uintx4*)(hrow + 32);
        floatx4 accA[4] = {{0,0,0,0},{0,0,0,0},{0,0,0,0},{0,0,0,0}};
        floatx4 accB[4] = {{0,0,0,0},{0,0,0,0},{0,0,0,0},{0,0,0,0}};
#pragma unroll
        for (int cb = 0; cb < 4; cb++) {
            accA[cb] = __builtin_amdgcn_mfma_f32_16x16x32_f16(h0f.h8, wa[0][cb].h8, accA[cb], 0, 0, 0);
            accB[cb] = __builtin_amdgcn_mfma_f32_16x16x32_f16(h0f.h8, wb[0][cb].h8, accB[cb], 0, 0, 0);
            accA[cb] = __builtin_amdgcn_mfma_f32_16x16x32_f16(h1f.h8, wa[1][cb].h8, accA[cb], 0, 0, 0);
            accB[cb] = __builtin_amdgcn_mfma_f32_16x16x32_f16(h1f.h8, wb[1][cb].h8, accB[cb], 0, 0, 0);
        }
#pragma unroll
        for (int cb = 0; cb < 4; cb++)
#pragma unroll
            for (int r = 0; r < 4; r++) {
                size_t o = (size_t)(nb + q * 4 + r) * 64 + cb * 16 + cl;
                A[o]  = f2h(accA[cb][r] + cav[cb]);
                Bb[o] = f2h(accB[cb][r] + cbv[cb]);
            }
    }
}

// ============ EdgeConv via f16 MFMA (R10-proven): single node/wave, 2-tile ILP ============
// (256,4): VGPR cap 128, kernel lands at 64 -> 8 waves/SIMD. R12's 2-node interleave (76 VGPR,
// 6 waves) regressed: TLP beats intra-wave ILP for this latency-bound gather loop.
__global__ __launch_bounds__(256, 4) void edge_mfma_kernel(
        const unsigned short* __restrict__ A, const unsigned short* __restrict__ Bb,
        const int* __restrict__ row_start, const unsigned short* __restrict__ sorted_src,
        const float* __restrict__ w2, const float* __restrict__ b2,
        unsigned short* __restrict__ catp, float* __restrict__ bnsNext) {
    __shared__ float r1[4][64], r2[4][64];
    int tid = threadIdx.x, lane = tid & 63, wid = tid >> 6;
    int kq = (lane >> 4) * 8;
    int cl = lane & 15;

    Uh bfr[2][4];
#pragma unroll
    for (int kh = 0; kh < 2; kh++)
#pragma unroll
        for (int cb = 0; cb < 4; cb++)
#pragma unroll
            for (int j = 0; j < 4; j++) {
                _Float16 w0 = (_Float16)w2[(kh * 32 + kq + 2 * j) * 64 + cb * 16 + cl];
                _Float16 w1 = (_Float16)w2[(kh * 32 + kq + 2 * j + 1) * 64 + cb * 16 + cl];
                bfr[kh][cb].h[j] = half2v{w0, w1};
            }
    float b2j = b2[lane];
    float s1 = 0.f, s2 = 0.f;
    const half2v zeroh = {(_Float16)0.f, (_Float16)0.f};

    for (int n = blockIdx.x * 4 + wid; n < N_NODES; n += gridDim.x * 4) {
        int beg = row_start[n], end = row_start[n + 1];
        const unsigned short* arow = A + (size_t)n * 64 + kq;
        Uh a0u, a1u;
        a0u.v = *(const uintx4*)(arow);
        a1u.v = *(const uintx4*)(arow + 32);
        floatx4 rmax0 = {-INFINITY, -INFINITY, -INFINITY, -INFINITY};
        floatx4 rmax1 = rmax0, rmax2 = rmax0, rmax3 = rmax0;

        auto tile = [&](uintx4 u0, uintx4 u1) {
            Uh b0u, b1u, f0, f1;
            b0u.v = u0; b1u.v = u1;
#pragma unroll
            for (int j = 0; j < 4; j++) {      // v_pk_add_f16 + v_pk_max_f16
                f0.h[j] = __builtin_elementwise_max(a0u.h[j] + b0u.h[j], zeroh);
                f1.h[j] = __builtin_elementwise_max(a1u.h[j] + b1u.h[j], zeroh);
            }
            floatx4 acc0 = {0.f, 0.f, 0.f, 0.f}, acc1 = acc0, acc2 = acc0, acc3 = acc0;
            acc0 = __builtin_amdgcn_mfma_f32_16x16x32_f16(f0.h8, bfr[0][0].h8, acc0, 0, 0, 0);
            acc1 = __builtin_amdgcn_mfma_f32_16x16x32_f16(f0.h8, bfr[0][1].h8, acc1, 0, 0, 0);
            acc2 = __builtin_amdgcn_mfma_f32_16x16x32_f16(f0.h8, bfr[0][2].h8, acc2, 0, 0, 0);
            acc3 = __builtin_amdgcn_mfma_f32_16x16x32_f16(f0.h8, bfr[0][3].h8, acc3, 0, 0, 0);
            acc0 = __builtin_amdgcn_mfma_f32_16x16x32_f16(f1.h8, bfr[1][0].h8, acc0, 0, 0, 0);
            acc1 = __builtin_amdgcn_mfma_f32_16x16x32_f16(f1.h8, bfr[1][1].h8, acc1, 0, 0, 0);
            acc2 = __builtin_amdgcn_mfma_f32_16x16x32_f16(f1.h8, bfr[1][2].h8, acc2, 0, 0, 0);
            acc3 = __builtin_amdgcn_mfma_f32_16x16x32_f16(f1.h8, bfr[1][3].h8, acc3, 0, 0, 0);
            rmax0 = __builtin_elementwise_max(rmax0, acc0);
            rmax1 = __builtin_elementwise_max(rmax1, acc1);
            rmax2 = __builtin_elementwise_max(rmax2, acc2);
            rmax3 = __builtin_elementwise_max(rmax3, acc3);
        };
        auto gather = [&](int p, uintx4& u0, uintx4& u1) {
            int srcm = sorted_src[p + cl];
            const unsigned short* brow = Bb + (size_t)srcm * 64 + kq;
            u0 = *(const uintx4*)(brow);
            u1 = *(const uintx4*)(brow + 32);
        };

        int p0 = beg;
        for (; p0 + 32 <= end; p0 += 32) {   // two tiles per iter: both gathers in flight
            uintx4 x0, x1, y0, y1;
            gather(p0, x0, x1);
            gather(p0 + 16, y0, y1);
            tile(x0, x1);
            tile(y0, y1);
        }
        if (p0 < end) {                       // odd-tile remainder
            uintx4 x0, x1;
            gather(p0, x0, x1);
            tile(x0, x1);
        }

        float v0 = fmaxf(fmaxf(rmax0.x, rmax0.y), fmaxf(rmax0.z, rmax0.w));
        float v1 = fmaxf(fmaxf(rmax1.x, rmax1.y), fmaxf(rmax1.z, rmax1.w));
        float v2 = fmaxf(fmaxf(rmax2.x, rmax2.y), fmaxf(rmax2.z, rmax2.w));
        float v3 = fmaxf(fmaxf(rmax3.x, rmax3.y), fmaxf(rmax3.z, rmax3.w));
        v0 = fmaxf(v0, __shfl_xor(v0, 16)); v0 = fmaxf(v0, __shfl_xor(v0, 32));
        v1 = fmaxf(v1, __shfl_xor(v1, 16)); v1 = fmaxf(v1, __shfl_xor(v1, 32));
        v2 = fmaxf(v2, __shfl_xor(v2, 16)); v2 = fmaxf(v2, __shfl_xor(v2, 32));
        v3 = fmaxf(v3, __shfl_xor(v3, 16)); v3 = fmaxf(v3, __shfl_xor(v3, 32));
        float vs = (lane & 32) ? ((lane & 16) ? v3 : v2) : ((lane & 16) ? v1 : v0);
        float v = fmaxf(vs + b2j, 0.f);  // -inf (empty node) -> 0; folds where(isfinite)+relu
        catp[(size_t)n * 64 + lane] = f2h(v);
        s1 += v; s2 += v * v;
    }

    if (bnsNext) {
        r1[wid][lane] = s1; r2[wid][lane] = s2;
        __syncthreads();
        if (tid < 64) {
            float a  = r1[0][tid] + r1[1][tid] + r1[2][tid] + r1[3][tid];
            float c2 = r2[0][tid] + r2[1][tid] + r2[2][tid] + r2[3][tid];
            int sl = blockIdx.x & (NSLICE - 1);
            atomicAdd(&bnsNext[sl * 128 + tid], a);
            atomicAdd(&bnsNext[sl * 128 + 64 + tid], c2);
        }
    }
}

// ============================ fused graph mean pool + MLP head + log_softmax ============================
__global__ __launch_bounds__(192) void poolhead_kernel(const unsigned short* __restrict__ cat0,
                                                       const unsigned short* __restrict__ cat1,
                                                       const unsigned short* __restrict__ cat2,
                                                       const int* __restrict__ batch,
                                                       const float* __restrict__ fc1w,
                                                       const float* __restrict__ fc1b,
                                                       const float* __restrict__ fc2w,
                                                       const float* __restrict__ fc2b,
                                                       float* __restrict__ out) {
    __shared__ int se[2];
    __shared__ float p[192];
    __shared__ float hid[128];
    __shared__ float z[10];
    __shared__ float lse;
    int g = blockIdx.x, tid = threadIdx.x;  // 192 threads
    if (tid < 2) {
        int target = g + tid;
        int lo = 0, hi = N_NODES;
        while (lo < hi) { int mid = (lo + hi) >> 1; if (batch[mid] < target) lo = mid + 1; else hi = mid; }
        se[tid] = lo;
    }
    __syncthreads();
    int s = se[0], e = se[1];
    const unsigned short* plane = (tid < 64) ? cat0 : ((tid < 128) ? cat1 : cat2);
    int col = tid & 63;
    float a0 = 0.f, a1 = 0.f, a2 = 0.f, a3 = 0.f;   // 4-way ILP in the pooling loop
    int r = s;
    for (; r + 4 <= e; r += 4) {
        a0 += h2f(plane[(size_t)(r + 0) * 64 + col]);
        a1 += h2f(plane[(size_t)(r + 1) * 64 + col]);
        a2 += h2f(plane[(size_t)(r + 2) * 64 + col]);
        a3 += h2f(plane[(size_t)(r + 3) * 64 + col]);
    }
    for (; r < e; r++) a0 += h2f(plane[(size_t)r * 64 + col]);
    float acc = (a0 + a1) + (a2 + a3);
    float denom = (e > s) ? (float)(e - s) : 1.0f;
    p[tid] = acc / denom;
    __syncthreads();
    if (tid < MLP_DIM) {
        float a = fc1b[tid];
        for (int k = 0; k < 192; k++) a = fmaf(p[k], fc1w[k * 128 + tid], a);
        hid[tid] = fmaxf(a, 0.f);
    }
    __syncthreads();
    if (tid < N_CLASSES) {
        float a = fc2b[tid];
        for (int k = 0; k < 128; k++) a = fmaf(hid[k], fc2w[k * 10 + tid], a);
        z[tid] = a;
    }
    __syncthreads();
    if (tid == 0) {
        float m = z[0];
        for (int i = 1; i < 10; i++) m = fmaxf(m, z[i]);
        float sm = 0.f;
        for (int i = 0; i < 10; i++) sm += expf(z[i] - m);
        lse = m + logf(sm);
    }
    __syncthreads();
    if (tid < N_CLASSES) out[g * 10 + tid] = z[tid] - lse;
}

// ============================ launch ============================
extern "C" void kernel_launch(void* const* d_in, const int* in_sizes, int n_in,
                              void* d_out, int out_size, void* d_ws, size_t ws_size,
                              hipStream_t stream) {
    (void)in_sizes; (void)n_in; (void)out_size; (void)ws_size;
    const float* x    = (const float*)d_in[0];
    const int*   ei   = (const int*)d_in[1];
    const int*   batch= (const int*)d_in[2];
    const float* fc0w = (const float*)d_in[3];
    const float* fc0b = (const float*)d_in[4];
    const float* fc1w = (const float*)d_in[5];
    const float* fc1b = (const float*)d_in[6];
    const float* fc2w = (const float*)d_in[7];
    const float* fc2b = (const float*)d_in[8];
    const int* src = ei;
    const int* dst = ei + N_EDGES;
    float* out = (float*)d_out;

    char* w = (char*)d_ws;
    size_t off = 0;
    auto alloc = [&](size_t bytes) -> void* {
        void* p = w + off;
        off = (off + bytes + 255) & ~(size_t)255;
        return p;
    };
    const size_t MAX_PAD_EDGES = (size_t)N_EDGES + 16 * (size_t)N_NODES;

    // zeroed-every-launch block: gcur[NB] | bns[3][NSLICE][128] | cnt[N_NODES]
    const size_t BNS_OFF = 1024;
    const size_t CNT_OFF = BNS_OFF + 3 * NSLICE * 128 * 4;
    const size_t ZBYTES  = CNT_OFF + (size_t)N_NODES * 4;
    char* zbase = (char*)alloc(ZBYTES);
    int*   gcur   = (int*)zbase;                     // NB ints (bucket cursors = final counts)
    float* bnsAll = (float*)(zbase + BNS_OFF);       // 3 * NSLICE * 128 floats
    int*   cnt    = (int*)(zbase + CNT_OFF);         // per-node degree (accumulated)

    unsigned short* cat0 = (unsigned short*)alloc((size_t)N_NODES * 64 * 2);  // 6.4 MB/plane (f16)
    unsigned short* cat1 = (unsigned short*)alloc((size_t)N_NODES * 64 * 2);
    unsigned short* cat2 = (unsigned short*)alloc((size_t)N_NODES * 64 * 2);
    unsigned short* h0   = (unsigned short*)alloc((size_t)N_NODES * 64 * 2);
    unsigned short* Ae   = (unsigned short*)alloc((size_t)N_NODES * 64 * 2);
    unsigned short* Be   = (unsigned short*)alloc((size_t)N_NODES * 64 * 2);
    unsigned* keys = (unsigned*)alloc((size_t)NB * CAPB * 4);    // 12.85 MB
    unsigned short* sorted_src = (unsigned short*)alloc(MAX_PAD_EDGES * 2);  // 4.8 MB
    int*   row_start = (int*)alloc((size_t)(N_NODES + 1) * 4);
    int*   bbase   = (int*)alloc(NB * 4);

    (void)hipMemsetAsync(zbase, 0, ZBYTES, stream);

    // --- two-level counting sort (no random global atomics — R11 lesson) ---
    pass1_kernel<<<(N_EDGES + CHUNK - 1) / CHUNK, 256, 0, stream>>>(src, dst, gcur, keys);
    node_count_kernel<<<NB * 2, 256, 0, stream>>>(keys, gcur, cnt);
    pscan_kernel<<<1, 256, 0, stream>>>(cnt, bbase, row_start);
    pass2_kernel<<<NB, 256, 0, stream>>>(keys, gcur, cnt, bbase, row_start, sorted_src);

    fc0_mfma_kernel<<<782, 256, 0, stream>>>(x, fc0w, fc0b, h0, bnsAll);

    unsigned short* planes[3] = {cat0, cat1, cat2};
    for (int blk = 0; blk < 3; blk++) {
        const float* g  = (const float*)d_in[9 + 6 * blk];
        const float* bb = (const float*)d_in[10 + 6 * blk];
        const float* w1 = (const float*)d_in[11 + 6 * blk];
        const float* b1 = (const float*)d_in[12 + 6 * blk];
        const float* w2 = (const float*)d_in[13 + 6 * blk];
        const float* b2 = (const float*)d_in[14 + 6 * blk];
        const unsigned short* hsrc = (blk == 0) ? h0 : planes[blk - 1];

        ab_mfma_kernel<<<782, 256, 0, stream>>>(hsrc, bnsAll + blk * NSLICE * 128,
                                                g, bb, w1, b1, Ae, Be);
        edge_mfma_kernel<<<2048, 256, 0, stream>>>(
            Ae, Be, row_start, sorted_src, w2, b2, planes[blk],
            (blk < 2) ? (bnsAll + (blk + 1) * NSLICE * 128) : nullptr);
    }

    poolhead_kernel<<<N_GRAPHS, 192, 0, stream>>>(cat0, cat1, cat2, batch,
                                                  fc1w, fc1b, fc2w, fc2b, out);
}

// Round 14
// 397.448 us; speedup vs baseline: 1.3730x; 1.0783x over previous
//
#include <hip/hip_runtime.h>
#include <math.h>

#define N_NODES 50000
#define N_TILES 3125      // N_NODES / 16 exactly
#define N_EDGES 1600000
#define F_IN 128
#define C 64
#define EF 64
#define N_GRAPHS 512
#define MLP_DIM 128
#define N_CLASSES 10
#define EPS 1e-5f
#define NB 196            // coarse buckets: dst>>8, 256 nodes each
#define CAPB 16384        // fixed bucket capacity (mean 8192, std ~90 -> safe)
#define CHUNK 4096        // edges per pass-1 block
#define NPASS1 391        // ceil(N_EDGES / CHUNK)
#define NFC0 782          // fc0 / ab MFMA blocks
#define NSLICE 8          // bn-stat atomic slices

typedef __attribute__((ext_vector_type(8))) _Float16 half8;
typedef __attribute__((ext_vector_type(2))) _Float16 half2v;
typedef __attribute__((ext_vector_type(4))) float floatx4;
typedef __attribute__((ext_vector_type(4))) unsigned uintx4;

union Uh { uintx4 v; half2v h[4]; half8 h8; };

__device__ __forceinline__ unsigned short f2h(float a) {
    union { _Float16 f; unsigned short u; } c;
    c.f = (_Float16)a;   // RNE
    return c.u;
}
__device__ __forceinline__ float h2f(unsigned short u) {
    union { unsigned short u; _Float16 f; } c;
    c.u = u;
    return (float)c.f;
}
__device__ __forceinline__ half2v pk2(float a, float b) {
    auto t = __builtin_amdgcn_cvt_pkrtz(a, b);   // __fp16 vec2 -> bit-cast (R6 lesson)
    union { decltype(t) i; half2v o; } c;
    c.i = t;
    return c.o;
}

// ============ FUSED: pass1 (blocks 0..NPASS1-1) + fc0 MFMA (blocks NPASS1..NPASS1+NFC0-1) ============
// Independent stages share one dispatch; pass1's latency hides under fc0's MFMA work.
// NO per-node global atomics in pass1 — R11: 1.6M random atomicAdds cost 57 MB cross-XCD writeback.
__global__ __launch_bounds__(256, 3) void fc0_pass1_kernel(
        const int* __restrict__ src, const int* __restrict__ dst,
        int* __restrict__ gcur, unsigned* __restrict__ keys,
        const float* __restrict__ x, const float* __restrict__ w,
        const float* __restrict__ b, unsigned short* __restrict__ h0,
        float* __restrict__ bns) {
    __shared__ int lcnt[NB], lbase[NB], lcnt2[NB];
    __shared__ float bl1[4][64], bl2[4][64];
    int tid = threadIdx.x;

    if (blockIdx.x < NPASS1) {
        // ---------------- pass1: bin edges into fixed-capacity buckets ----------------
        int e0 = blockIdx.x * CHUNK;
        unsigned k[CHUNK / 256];
        int bk[CHUNK / 256];
        for (int i = tid; i < NB; i += 256) lcnt[i] = 0;
        __syncthreads();
#pragma unroll
        for (int i = 0; i < CHUNK / 256; i++) {
            int e = e0 + i * 256 + tid;
            if (e < N_EDGES) {
                int d = dst[e];
                k[i] = ((unsigned)d << 16) | (unsigned)src[e];
                bk[i] = d >> 8;
                atomicAdd(&lcnt[bk[i]], 1);
            } else bk[i] = -1;
        }
        __syncthreads();
        for (int i = tid; i < NB; i += 256) {
            int c = lcnt[i];
            lbase[i] = c ? atomicAdd(&gcur[i], c) : 0;
            lcnt2[i] = 0;
        }
        __syncthreads();
#pragma unroll
        for (int i = 0; i < CHUNK / 256; i++) {
            if (bk[i] >= 0) {
                int r = atomicAdd(&lcnt2[bk[i]], 1);
                keys[(size_t)bk[i] * CAPB + lbase[bk[i]] + r] = k[i];
            }
        }
        return;
    }

    // ---------------- fc0: h0[16-node tile] = x @ fc0_w + b (f16) + BN stats ----------------
    int bid = blockIdx.x - NPASS1;
    int lane = tid & 63, wid = tid >> 6;
    int q = lane >> 4, cl = lane & 15, kq = q * 8;

    Uh wf[4][4];
#pragma unroll
    for (int kh = 0; kh < 4; kh++)
#pragma unroll
        for (int cb = 0; cb < 4; cb++)
#pragma unroll
            for (int j = 0; j < 4; j++) {
                int k0 = kh * 32 + kq + 2 * j;
                int col = cb * 16 + cl;
                wf[kh][cb].h[j] = pk2(w[k0 * 64 + col], w[(k0 + 1) * 64 + col]);
            }
    float bv[4];
#pragma unroll
    for (int cb = 0; cb < 4; cb++) bv[cb] = b[cb * 16 + cl];
    float s1[4] = {0, 0, 0, 0}, s2[4] = {0, 0, 0, 0};

    for (int t = bid * 4 + wid; t < N_TILES; t += NFC0 * 4) {
        int nb = t * 16;
        floatx4 acc[4] = {{0,0,0,0},{0,0,0,0},{0,0,0,0},{0,0,0,0}};
#pragma unroll
        for (int kh = 0; kh < 4; kh++) {
            const float* xr = x + (size_t)(nb + cl) * F_IN + kh * 32 + kq;
            floatx4 xa = *(const floatx4*)xr;
            floatx4 xb = *(const floatx4*)(xr + 4);
            Uh xf;
            xf.h[0] = pk2(xa.x, xa.y); xf.h[1] = pk2(xa.z, xa.w);
            xf.h[2] = pk2(xb.x, xb.y); xf.h[3] = pk2(xb.z, xb.w);
#pragma unroll
            for (int cb = 0; cb < 4; cb++)
                acc[cb] = __builtin_amdgcn_mfma_f32_16x16x32_f16(xf.h8, wf[kh][cb].h8, acc[cb], 0, 0, 0);
        }
#pragma unroll
        for (int cb = 0; cb < 4; cb++)
#pragma unroll
            for (int r = 0; r < 4; r++) {
                float v = acc[cb][r] + bv[cb];            // node = nb+q*4+r, col = cb*16+cl
                h0[(size_t)(nb + q * 4 + r) * 64 + cb * 16 + cl] = f2h(v);
                s1[cb] += v; s2[cb] += v * v;
            }
    }
#pragma unroll
    for (int cb = 0; cb < 4; cb++) {
        s1[cb] += __shfl_xor(s1[cb], 16); s1[cb] += __shfl_xor(s1[cb], 32);
        s2[cb] += __shfl_xor(s2[cb], 16); s2[cb] += __shfl_xor(s2[cb], 32);
    }
    if (lane < 16) {
#pragma unroll
        for (int cb = 0; cb < 4; cb++) { bl1[wid][cb * 16 + lane] = s1[cb]; bl2[wid][cb * 16 + lane] = s2[cb]; }
    }
    __syncthreads();
    if (tid < 64) {
        float a  = bl1[0][tid] + bl1[1][tid] + bl1[2][tid] + bl1[3][tid];
        float c2 = bl2[0][tid] + bl2[1][tid] + bl2[2][tid] + bl2[3][tid];
        int sl = bid & (NSLICE - 1);
        atomicAdd(&bns[sl * 128 + tid], a);
        atomicAdd(&bns[sl * 128 + 64 + tid], c2);
    }
}

// ============ ab body (device): A = bn(h)@WA + cA, B = bn(h)@WB + cB (both f16) ============
__device__ __forceinline__ void ab_body(int bid, int tid,
                                        const unsigned short* __restrict__ h,
                                        const float* __restrict__ bns,
                                        const float* __restrict__ g,
                                        const float* __restrict__ bb,
                                        const float* __restrict__ w1,
                                        const float* __restrict__ b1,
                                        unsigned short* __restrict__ A,
                                        unsigned short* __restrict__ Bb,
                                        float* scale, float* shift, float* cab) {
    int lane = tid & 63, wid = tid >> 6;
    int q = lane >> 4, cl = lane & 15, kq = q * 8;

    if (tid < 64) {
        float s1v = 0.f, s2v = 0.f;
#pragma unroll
        for (int s = 0; s < NSLICE; s++) { s1v += bns[s * 128 + tid]; s2v += bns[s * 128 + 64 + tid]; }
        float mu  = s1v * (1.0f / N_NODES);
        float var = s2v * (1.0f / N_NODES) - mu * mu;
        float sc  = g[tid] * rsqrtf(var + EPS);
        scale[tid] = sc;
        shift[tid] = bb[tid] - mu * sc;
    }
    __syncthreads();
    if (tid < 128) {
        int j = tid & 63;
        float acc = (tid < 64) ? b1[j] : 0.f;
        for (int k = 0; k < 64; k++) {
            float wa_ = w1[k * EF + j], wb_ = w1[(64 + k) * EF + j];
            acc = fmaf(shift[k], (tid < 64) ? (wa_ - wb_) : wb_, acc);
        }
        cab[tid] = acc;
    }
    Uh wa[2][4], wb[2][4];
#pragma unroll
    for (int kh = 0; kh < 2; kh++)
#pragma unroll
        for (int cb = 0; cb < 4; cb++)
#pragma unroll
            for (int j = 0; j < 4; j++) {
                int k0 = kh * 32 + kq + 2 * j;
                int col = cb * 16 + cl;
                float sa = scale[k0], sb = scale[k0 + 1];
                float a0 = w1[k0 * EF + col], b0 = w1[(64 + k0) * EF + col];
                float a1 = w1[(k0 + 1) * EF + col], b1v = w1[(64 + k0 + 1) * EF + col];
                wa[kh][cb].h[j] = pk2(sa * (a0 - b0), sb * (a1 - b1v));
                wb[kh][cb].h[j] = pk2(sa * b0, sb * b1v);
            }
    __syncthreads();
    float cav[4], cbv[4];
#pragma unroll
    for (int cb = 0; cb < 4; cb++) { cav[cb] = cab[cb * 16 + cl]; cbv[cb] = cab[64 + cb * 16 + cl]; }

    for (int t = bid * 4 + wid; t < N_TILES; t += NFC0 * 4) {
        int nb = t * 16;
        const unsigned short* hrow = h + (size_t)(nb + cl) * 64 + kq;
        Uh h0f, h1f;
        h0f.v = *(const uintx4*)hrow;
        h1f.v = *(const uintx4*)(hrow + 32);
        floatx4 accA[4] = {{0,0,0,0},{0,0,0,0},{0,0,0,0},{0,0,0,0}};
        floatx4 accB[4] = {{0,0,0,0},{0,0,0,0},{0,0,0,0},{0,0,0,0}};
#pragma unroll
        for (int cb = 0; cb < 4; cb++) {
            accA[cb] = __builtin_amdgcn_mfma_f32_16x16x32_f16(h0f.h8, wa[0][cb].h8, accA[cb], 0, 0, 0);
            accB[cb] = __builtin_amdgcn_mfma_f32_16x16x32_f16(h0f.h8, wb[0][cb].h8, accB[cb], 0, 0, 0);
            accA[cb] = __builtin_amdgcn_mfma_f32_16x16x32_f16(h1f.h8, wa[1][cb].h8, accA[cb], 0, 0, 0);
            accB[cb] = __builtin_amdgcn_mfma_f32_16x16x32_f16(h1f.h8, wb[1][cb].h8, accB[cb], 0, 0, 0);
        }
#pragma unroll
        for (int cb = 0; cb < 4; cb++)
#pragma unroll
            for (int r = 0; r < 4; r++) {
                size_t o = (size_t)(nb + q * 4 + r) * 64 + cb * 16 + cl;
                A[o]  = f2h(accA[cb][r] + cav[cb]);
                Bb[o] = f2h(accB[cb][r] + cbv[cb]);
            }
    }
}

// ============ FUSED: node_count (blocks 0..2*NB-1) + ab for block 0 (rest) ============
__global__ __launch_bounds__(256, 4) void nc_ab_kernel(
        const unsigned* __restrict__ keys, const int* __restrict__ bcnt,
        int* __restrict__ cnt,
        const unsigned short* __restrict__ h, const float* __restrict__ bns,
        const float* __restrict__ g, const float* __restrict__ bb,
        const float* __restrict__ w1, const float* __restrict__ b1,
        unsigned short* __restrict__ A, unsigned short* __restrict__ Bb) {
    __shared__ int lc[256];
    __shared__ float scale[64], shift[64], cab[128];
    int tid = threadIdx.x;
    if (blockIdx.x < 2 * NB) {
        // per-node degree: 2 blocks/bucket, LDS hist + coalesced 2-way global atomics
        int b = blockIdx.x >> 1, half = blockIdx.x & 1;
        lc[tid] = 0;
        __syncthreads();
        int nk = bcnt[b];
        int chunk = (nk + 1) >> 1;
        int beg = half * chunk;
        int end = beg + chunk; if (end > nk) end = nk;
        const unsigned* kb = keys + (size_t)b * CAPB;
        for (int p = beg + tid; p < end; p += 256)
            atomicAdd(&lc[(kb[p] >> 16) & 255], 1);
        __syncthreads();
        int node = b * 256 + tid;
        if (node < N_NODES && lc[tid]) atomicAdd(&cnt[node], lc[tid]);
        return;
    }
    ab_body(blockIdx.x - 2 * NB, tid, h, bns, g, bb, w1, b1, A, Bb, scale, shift, cab);
}

// ============ plain ab kernel (blocks 1 and 2) ============
__global__ __launch_bounds__(256, 4) void ab_mfma_kernel(
        const unsigned short* __restrict__ h, const float* __restrict__ bns,
        const float* __restrict__ g, const float* __restrict__ bb,
        const float* __restrict__ w1, const float* __restrict__ b1,
        unsigned short* __restrict__ A, unsigned short* __restrict__ Bb) {
    __shared__ float scale[64], shift[64], cab[128];
    ab_body(blockIdx.x, threadIdx.x, h, bns, g, bb, w1, b1, A, Bb, scale, shift, cab);
}

// ==== pass2: local padded scan + atomic-ticket bucket base -> row_start, scatter + pad fill ====
// Bucket segments land in arbitrary order; edge derives ends from cnt[n] (order-free CSR).
__global__ __launch_bounds__(256) void pass2_kernel(const unsigned* __restrict__ keys,
                                                    const int* __restrict__ bcnt,
                                                    const int* __restrict__ cnt,
                                                    int* __restrict__ gtotal,
                                                    int* __restrict__ row_start,
                                                    unsigned short* __restrict__ sorted_src) {
    __shared__ int loc[256], rs[256], cur[256];
    __shared__ int base;
    int tid = threadIdx.x, b = blockIdx.x;
    int node = b * 256 + tid;
    int c = (node < N_NODES) ? cnt[node] : 0;
    int pc = (c + 15) & ~15;
    loc[tid] = pc;
    cur[tid] = 0;
    __syncthreads();
    for (int off = 1; off < 256; off <<= 1) {
        int t = (tid >= off) ? loc[tid - off] : 0;
        __syncthreads();
        loc[tid] += t;
        __syncthreads();
    }
    if (tid == 255) base = atomicAdd(gtotal, loc[255]);
    __syncthreads();
    int myrs = base + loc[tid] - pc;  // exclusive within bucket + ticket base
    rs[tid] = myrs;
    if (node < N_NODES) row_start[node] = myrs;
    __syncthreads();
    int beg = b * CAPB, end = beg + bcnt[b];
    for (int p = beg + tid; p < end; p += 256) {
        unsigned k = keys[p];
        int lidx = (k >> 16) & 255;
        int r = atomicAdd(&cur[lidx], 1);
        sorted_src[rs[lidx] + r] = (unsigned short)(k & 0xFFFFu);
    }
    __syncthreads();
    if (node < N_NODES) {
        int deg = cur[tid];
        if (deg > 0) {
            unsigned short s0 = sorted_src[myrs];
            for (int p = myrs + deg; p < myrs + pc; p++) sorted_src[p] = s0;  // max idempotent
        }
    }
}

// ============ EdgeConv via f16 MFMA (R10-proven): single node/wave, 2-tile ILP ============
// (256,4): VGPR 64 -> 8 waves/SIMD. R12: 2-node interleave (76 VGPR, 6 waves) regressed —
// TLP beats intra-wave ILP for this latency-bound gather loop. Ends from cnt[n] (ticket CSR).
__global__ __launch_bounds__(256, 4) void edge_mfma_kernel(
        const unsigned short* __restrict__ A, const unsigned short* __restrict__ Bb,
        const int* __restrict__ row_start, const int* __restrict__ cnt,
        const unsigned short* __restrict__ sorted_src,
        const float* __restrict__ w2, const float* __restrict__ b2,
        unsigned short* __restrict__ catp, float* __restrict__ bnsNext) {
    __shared__ float r1[4][64], r2[4][64];
    int tid = threadIdx.x, lane = tid & 63, wid = tid >> 6;
    int kq = (lane >> 4) * 8;
    int cl = lane & 15;

    Uh bfr[2][4];
#pragma unroll
    for (int kh = 0; kh < 2; kh++)
#pragma unroll
        for (int cb = 0; cb < 4; cb++)
#pragma unroll
            for (int j = 0; j < 4; j++) {
                _Float16 w0 = (_Float16)w2[(kh * 32 + kq + 2 * j) * 64 + cb * 16 + cl];
                _Float16 w1 = (_Float16)w2[(kh * 32 + kq + 2 * j + 1) * 64 + cb * 16 + cl];
                bfr[kh][cb].h[j] = half2v{w0, w1};
            }
    float b2j = b2[lane];
    float s1 = 0.f, s2 = 0.f;
    const half2v zeroh = {(_Float16)0.f, (_Float16)0.f};

    for (int n = blockIdx.x * 4 + wid; n < N_NODES; n += gridDim.x * 4) {
        int beg = row_start[n];
        int end = beg + ((cnt[n] + 15) & ~15);
        const unsigned short* arow = A + (size_t)n * 64 + kq;
        Uh a0u, a1u;
        a0u.v = *(const uintx4*)(arow);
        a1u.v = *(const uintx4*)(arow + 32);
        floatx4 rmax0 = {-INFINITY, -INFINITY, -INFINITY, -INFINITY};
        floatx4 rmax1 = rmax0, rmax2 = rmax0, rmax3 = rmax0;

        auto tile = [&](uintx4 u0, uintx4 u1) {
            Uh b0u, b1u, f0, f1;
            b0u.v = u0; b1u.v = u1;
#pragma unroll
            for (int j = 0; j < 4; j++) {      // v_pk_add_f16 + v_pk_max_f16
                f0.h[j] = __builtin_elementwise_max(a0u.h[j] + b0u.h[j], zeroh);
                f1.h[j] = __builtin_elementwise_max(a1u.h[j] + b1u.h[j], zeroh);
            }
            floatx4 acc0 = {0.f, 0.f, 0.f, 0.f}, acc1 = acc0, acc2 = acc0, acc3 = acc0;
            acc0 = __builtin_amdgcn_mfma_f32_16x16x32_f16(f0.h8, bfr[0][0].h8, acc0, 0, 0, 0);
            acc1 = __builtin_amdgcn_mfma_f32_16x16x32_f16(f0.h8, bfr[0][1].h8, acc1, 0, 0, 0);
            acc2 = __builtin_amdgcn_mfma_f32_16x16x32_f16(f0.h8, bfr[0][2].h8, acc2, 0, 0, 0);
            acc3 = __builtin_amdgcn_mfma_f32_16x16x32_f16(f0.h8, bfr[0][3].h8, acc3, 0, 0, 0);
            acc0 = __builtin_amdgcn_mfma_f32_16x16x32_f16(f1.h8, bfr[1][0].h8, acc0, 0, 0, 0);
            acc1 = __builtin_amdgcn_mfma_f32_16x16x32_f16(f1.h8, bfr[1][1].h8, acc1, 0, 0, 0);
            acc2 = __builtin_amdgcn_mfma_f32_16x16x32_f16(f1.h8, bfr[1][2].h8, acc2, 0, 0, 0);
            acc3 = __builtin_amdgcn_mfma_f32_16x16x32_f16(f1.h8, bfr[1][3].h8, acc3, 0, 0, 0);
            rmax0 = __builtin_elementwise_max(rmax0, acc0);
            rmax1 = __builtin_elementwise_max(rmax1, acc1);
            rmax2 = __builtin_elementwise_max(rmax2, acc2);
            rmax3 = __builtin_elementwise_max(rmax3, acc3);
        };
        auto gather = [&](int p, uintx4& u0, uintx4& u1) {
            int srcm = sorted_src[p + cl];
            const unsigned short* brow = Bb + (size_t)srcm * 64 + kq;
            u0 = *(const uintx4*)(brow);
            u1 = *(const uintx4*)(brow + 32);
        };

        int p0 = beg;
        for (; p0 + 32 <= end; p0 += 32) {   // two tiles per iter: both gathers in flight
            uintx4 x0, x1, y0, y1;
            gather(p0, x0, x1);
            gather(p0 + 16, y0, y1);
            tile(x0, x1);
            tile(y0, y1);
        }
        if (p0 < end) {                       // odd-tile remainder
            uintx4 x0, x1;
            gather(p0, x0, x1);
            tile(x0, x1);
        }

        float v0 = fmaxf(fmaxf(rmax0.x, rmax0.y), fmaxf(rmax0.z, rmax0.w));
        float v1 = fmaxf(fmaxf(rmax1.x, rmax1.y), fmaxf(rmax1.z, rmax1.w));
        float v2 = fmaxf(fmaxf(rmax2.x, rmax2.y), fmaxf(rmax2.z, rmax2.w));
        float v3 = fmaxf(fmaxf(rmax3.x, rmax3.y), fmaxf(rmax3.z, rmax3.w));
        v0 = fmaxf(v0, __shfl_xor(v0, 16)); v0 = fmaxf(v0, __shfl_xor(v0, 32));
        v1 = fmaxf(v1, __shfl_xor(v1, 16)); v1 = fmaxf(v1, __shfl_xor(v1, 32));
        v2 = fmaxf(v2, __shfl_xor(v2, 16)); v2 = fmaxf(v2, __shfl_xor(v2, 32));
        v3 = fmaxf(v3, __shfl_xor(v3, 16)); v3 = fmaxf(v3, __shfl_xor(v3, 32));
        float vs = (lane & 32) ? ((lane & 16) ? v3 : v2) : ((lane & 16) ? v1 : v0);
        float v = fmaxf(vs + b2j, 0.f);  // -inf (empty node) -> 0; folds where(isfinite)+relu
        catp[(size_t)n * 64 + lane] = f2h(v);
        s1 += v; s2 += v * v;
    }

    if (bnsNext) {
        r1[wid][lane] = s1; r2[wid][lane] = s2;
        __syncthreads();
        if (tid < 64) {
            float a  = r1[0][tid] + r1[1][tid] + r1[2][tid] + r1[3][tid];
            float c2 = r2[0][tid] + r2[1][tid] + r2[2][tid] + r2[3][tid];
            int sl = blockIdx.x & (NSLICE - 1);
            atomicAdd(&bnsNext[sl * 128 + tid], a);
            atomicAdd(&bnsNext[sl * 128 + 64 + tid], c2);
        }
    }
}

// ============================ fused graph mean pool + MLP head + log_softmax ============================
__global__ __launch_bounds__(192) void poolhead_kernel(const unsigned short* __restrict__ cat0,
                                                       const unsigned short* __restrict__ cat1,
                                                       const unsigned short* __restrict__ cat2,
                                                       const int* __restrict__ batch,
                                                       const float* __restrict__ fc1w,
                                                       const float* __restrict__ fc1b,
                                                       const float* __restrict__ fc2w,
                                                       const float* __restrict__ fc2b,
                                                       float* __restrict__ out) {
    __shared__ int se[2];
    __shared__ float p[192];
    __shared__ float hid[128];
    __shared__ float z[10];
    __shared__ float lse;
    int g = blockIdx.x, tid = threadIdx.x;  // 192 threads
    if (tid < 2) {
        int target = g + tid;
        int lo = 0, hi = N_NODES;
        while (lo < hi) { int mid = (lo + hi) >> 1; if (batch[mid] < target) lo = mid + 1; else hi = mid; }
        se[tid] = lo;
    }
    __syncthreads();
    int s = se[0], e = se[1];
    const unsigned short* plane = (tid < 64) ? cat0 : ((tid < 128) ? cat1 : cat2);
    int col = tid & 63;
    float a0 = 0.f, a1 = 0.f, a2 = 0.f, a3 = 0.f;   // 4-way ILP in the pooling loop
    int r = s;
    for (; r + 4 <= e; r += 4) {
        a0 += h2f(plane[(size_t)(r + 0) * 64 + col]);
        a1 += h2f(plane[(size_t)(r + 1) * 64 + col]);
        a2 += h2f(plane[(size_t)(r + 2) * 64 + col]);
        a3 += h2f(plane[(size_t)(r + 3) * 64 + col]);
    }
    for (; r < e; r++) a0 += h2f(plane[(size_t)r * 64 + col]);
    float acc = (a0 + a1) + (a2 + a3);
    float denom = (e > s) ? (float)(e - s) : 1.0f;
    p[tid] = acc / denom;
    __syncthreads();
    if (tid < MLP_DIM) {
        float a = fc1b[tid];
        for (int k = 0; k < 192; k++) a = fmaf(p[k], fc1w[k * 128 + tid], a);
        hid[tid] = fmaxf(a, 0.f);
    }
    __syncthreads();
    if (tid < N_CLASSES) {
        float a = fc2b[tid];
        for (int k = 0; k < 128; k++) a = fmaf(hid[k], fc2w[k * 10 + tid], a);
        z[tid] = a;
    }
    __syncthreads();
    if (tid == 0) {
        float m = z[0];
        for (int i = 1; i < 10; i++) m = fmaxf(m, z[i]);
        float sm = 0.f;
        for (int i = 0; i < 10; i++) sm += expf(z[i] - m);
        lse = m + logf(sm);
    }
    __syncthreads();
    if (tid < N_CLASSES) out[g * 10 + tid] = z[tid] - lse;
}

// ============================ launch ============================
extern "C" void kernel_launch(void* const* d_in, const int* in_sizes, int n_in,
                              void* d_out, int out_size, void* d_ws, size_t ws_size,
                              hipStream_t stream) {
    (void)in_sizes; (void)n_in; (void)out_size; (void)ws_size;
    const float* x    = (const float*)d_in[0];
    const int*   ei   = (const int*)d_in[1];
    const int*   batch= (const int*)d_in[2];
    const float* fc0w = (const float*)d_in[3];
    const float* fc0b = (const float*)d_in[4];
    const float* fc1w = (const float*)d_in[5];
    const float* fc1b = (const float*)d_in[6];
    const float* fc2w = (const float*)d_in[7];
    const float* fc2b = (const float*)d_in[8];
    const int* src = ei;
    const int* dst = ei + N_EDGES;
    float* out = (float*)d_out;

    char* w = (char*)d_ws;
    size_t off = 0;
    auto alloc = [&](size_t bytes) -> void* {
        void* p = w + off;
        off = (off + bytes + 255) & ~(size_t)255;
        return p;
    };
    const size_t MAX_PAD_EDGES = (size_t)N_EDGES + 16 * (size_t)N_NODES;

    // zeroed-every-launch block: gcur[NB] | gtotal | bns[3][NSLICE][128] | cnt[N_NODES]
    const size_t BNS_OFF = 1280;
    const size_t CNT_OFF = BNS_OFF + 3 * NSLICE * 128 * 4;
    const size_t ZBYTES  = CNT_OFF + (size_t)N_NODES * 4;
    char* zbase = (char*)alloc(ZBYTES);
    int*   gcur   = (int*)zbase;                     // NB ints (bucket cursors = final counts)
    int*   gtotal = (int*)(zbase + 1024);            // pass2 ticket
    float* bnsAll = (float*)(zbase + BNS_OFF);       // 3 * NSLICE * 128 floats
    int*   cnt    = (int*)(zbase + CNT_OFF);         // per-node degree

    unsigned short* cat0 = (unsigned short*)alloc((size_t)N_NODES * 64 * 2);  // 6.4 MB/plane (f16)
    unsigned short* cat1 = (unsigned short*)alloc((size_t)N_NODES * 64 * 2);
    unsigned short* cat2 = (unsigned short*)alloc((size_t)N_NODES * 64 * 2);
    unsigned short* h0   = (unsigned short*)alloc((size_t)N_NODES * 64 * 2);
    unsigned short* Ae   = (unsigned short*)alloc((size_t)N_NODES * 64 * 2);
    unsigned short* Be   = (unsigned short*)alloc((size_t)N_NODES * 64 * 2);
    unsigned* keys = (unsigned*)alloc((size_t)NB * CAPB * 4);    // 12.85 MB
    unsigned short* sorted_src = (unsigned short*)alloc(MAX_PAD_EDGES * 2);  // 4.8 MB
    int*   row_start = (int*)alloc((size_t)N_NODES * 4);

    (void)hipMemsetAsync(zbase, 0, ZBYTES, stream);

    // D1: pass1 + fc0 fused (independent; pass1 hides under fc0)
    fc0_pass1_kernel<<<NPASS1 + NFC0, 256, 0, stream>>>(src, dst, gcur, keys,
                                                        x, fc0w, fc0b, h0, bnsAll);
    // D2: node_count + ab(block0) fused
    nc_ab_kernel<<<2 * NB + NFC0, 256, 0, stream>>>(
        keys, gcur, cnt, h0, bnsAll,
        (const float*)d_in[9], (const float*)d_in[10],
        (const float*)d_in[11], (const float*)d_in[12], Ae, Be);
    // D3: pass2 (ticket-based row_start + scatter + pad fill)
    pass2_kernel<<<NB, 256, 0, stream>>>(keys, gcur, cnt, gtotal, row_start, sorted_src);

    unsigned short* planes[3] = {cat0, cat1, cat2};
    for (int blk = 0; blk < 3; blk++) {
        const float* w2 = (const float*)d_in[13 + 6 * blk];
        const float* b2 = (const float*)d_in[14 + 6 * blk];
        if (blk > 0) {
            ab_mfma_kernel<<<NFC0, 256, 0, stream>>>(
                planes[blk - 1], bnsAll + blk * NSLICE * 128,
                (const float*)d_in[9 + 6 * blk], (const float*)d_in[10 + 6 * blk],
                (const float*)d_in[11 + 6 * blk], (const float*)d_in[12 + 6 * blk], Ae, Be);
        }
        edge_mfma_kernel<<<2048, 256, 0, stream>>>(
            Ae, Be, row_start, cnt, sorted_src, w2, b2, planes[blk],
            (blk < 2) ? (bnsAll + (blk + 1) * NSLICE * 128) : nullptr);
    }

    poolhead_kernel<<<N_GRAPHS, 192, 0, stream>>>(cat0, cat1, cat2, batch,
                                                  fc1w, fc1b, fc2w, fc2b, out);
}

// Round 15
// 390.866 us; speedup vs baseline: 1.3961x; 1.0168x over previous
//
#include <hip/hip_runtime.h>
#include <math.h>

#define N_NODES 50000
#define N_TILES 3125      // N_NODES / 16 exactly
#define N_EDGES 1600000
#define F_IN 128
#define C 64
#define EF 64
#define N_GRAPHS 512
#define MLP_DIM 128
#define N_CLASSES 10
#define EPS 1e-5f
#define NB 196            // coarse buckets: dst>>8, 256 nodes each
#define CAPB 16384        // fixed bucket capacity (mean 8192, std ~90 -> safe)
#define CHUNK 4096        // edges per pass-1 block
#define NPASS1 391        // ceil(N_EDGES / CHUNK)
#define NFC0 782          // fc0 / ab MFMA blocks
#define NSLICE 8          // bn-stat atomic slices

typedef __attribute__((ext_vector_type(8))) _Float16 half8;
typedef __attribute__((ext_vector_type(2))) _Float16 half2v;
typedef __attribute__((ext_vector_type(4))) float floatx4;
typedef __attribute__((ext_vector_type(4))) unsigned uintx4;

union Uh { uintx4 v; half2v h[4]; half8 h8; };

__device__ __forceinline__ unsigned short f2h(float a) {
    union { _Float16 f; unsigned short u; } c;
    c.f = (_Float16)a;   // RNE
    return c.u;
}
__device__ __forceinline__ float h2f(unsigned short u) {
    union { unsigned short u; _Float16 f; } c;
    c.u = u;
    return (float)c.f;
}
__device__ __forceinline__ half2v pk2(float a, float b) {
    auto t = __builtin_amdgcn_cvt_pkrtz(a, b);   // __fp16 vec2 -> bit-cast (R6 lesson)
    union { decltype(t) i; half2v o; } c;
    c.i = t;
    return c.o;
}

// ============ FUSED: pass1 (blocks 0..NPASS1-1) + fc0 MFMA (blocks NPASS1..) ============
// Independent stages share one dispatch; pass1's latency hides under fc0's MFMA work.
// NO per-node global atomics in pass1 — R11: 1.6M random atomicAdds cost 57 MB cross-XCD writeback.
__global__ __launch_bounds__(256, 3) void fc0_pass1_kernel(
        const int* __restrict__ src, const int* __restrict__ dst,
        int* __restrict__ gcur, unsigned* __restrict__ keys,
        const float* __restrict__ x, const float* __restrict__ w,
        const float* __restrict__ b, unsigned short* __restrict__ h0,
        float* __restrict__ bns) {
    __shared__ int lcnt[NB], lbase[NB], lcnt2[NB];
    __shared__ float bl1[4][64], bl2[4][64];
    int tid = threadIdx.x;

    if (blockIdx.x < NPASS1) {
        // ---------------- pass1: bin edges into fixed-capacity buckets ----------------
        int e0 = blockIdx.x * CHUNK;
        unsigned k[CHUNK / 256];
        int bk[CHUNK / 256];
        for (int i = tid; i < NB; i += 256) lcnt[i] = 0;
        __syncthreads();
#pragma unroll
        for (int i = 0; i < CHUNK / 256; i++) {
            int e = e0 + i * 256 + tid;
            if (e < N_EDGES) {
                int d = dst[e];
                k[i] = ((unsigned)d << 16) | (unsigned)src[e];
                bk[i] = d >> 8;
                atomicAdd(&lcnt[bk[i]], 1);
            } else bk[i] = -1;
        }
        __syncthreads();
        for (int i = tid; i < NB; i += 256) {
            int c = lcnt[i];
            lbase[i] = c ? atomicAdd(&gcur[i], c) : 0;
            lcnt2[i] = 0;
        }
        __syncthreads();
#pragma unroll
        for (int i = 0; i < CHUNK / 256; i++) {
            if (bk[i] >= 0) {
                int r = atomicAdd(&lcnt2[bk[i]], 1);
                keys[(size_t)bk[i] * CAPB + lbase[bk[i]] + r] = k[i];
            }
        }
        return;
    }

    // ---------------- fc0: h0[16-node tile] = x @ fc0_w + b (f16) + BN stats ----------------
    int bid = blockIdx.x - NPASS1;
    int lane = tid & 63, wid = tid >> 6;
    int q = lane >> 4, cl = lane & 15, kq = q * 8;

    Uh wf[4][4];
#pragma unroll
    for (int kh = 0; kh < 4; kh++)
#pragma unroll
        for (int cb = 0; cb < 4; cb++)
#pragma unroll
            for (int j = 0; j < 4; j++) {
                int k0 = kh * 32 + kq + 2 * j;
                int col = cb * 16 + cl;
                wf[kh][cb].h[j] = pk2(w[k0 * 64 + col], w[(k0 + 1) * 64 + col]);
            }
    float bv[4];
#pragma unroll
    for (int cb = 0; cb < 4; cb++) bv[cb] = b[cb * 16 + cl];
    float s1[4] = {0, 0, 0, 0}, s2[4] = {0, 0, 0, 0};

    for (int t = bid * 4 + wid; t < N_TILES; t += NFC0 * 4) {
        int nb = t * 16;
        floatx4 acc[4] = {{0,0,0,0},{0,0,0,0},{0,0,0,0},{0,0,0,0}};
#pragma unroll
        for (int kh = 0; kh < 4; kh++) {
            const float* xr = x + (size_t)(nb + cl) * F_IN + kh * 32 + kq;
            floatx4 xa = *(const floatx4*)xr;
            floatx4 xb = *(const floatx4*)(xr + 4);
            Uh xf;
            xf.h[0] = pk2(xa.x, xa.y); xf.h[1] = pk2(xa.z, xa.w);
            xf.h[2] = pk2(xb.x, xb.y); xf.h[3] = pk2(xb.z, xb.w);
#pragma unroll
            for (int cb = 0; cb < 4; cb++)
                acc[cb] = __builtin_amdgcn_mfma_f32_16x16x32_f16(xf.h8, wf[kh][cb].h8, acc[cb], 0, 0, 0);
        }
#pragma unroll
        for (int cb = 0; cb < 4; cb++)
#pragma unroll
            for (int r = 0; r < 4; r++) {
                float v = acc[cb][r] + bv[cb];            // node = nb+q*4+r, col = cb*16+cl
                h0[(size_t)(nb + q * 4 + r) * 64 + cb * 16 + cl] = f2h(v);
                s1[cb] += v; s2[cb] += v * v;
            }
    }
#pragma unroll
    for (int cb = 0; cb < 4; cb++) {
        s1[cb] += __shfl_xor(s1[cb], 16); s1[cb] += __shfl_xor(s1[cb], 32);
        s2[cb] += __shfl_xor(s2[cb], 16); s2[cb] += __shfl_xor(s2[cb], 32);
    }
    if (lane < 16) {
#pragma unroll
        for (int cb = 0; cb < 4; cb++) { bl1[wid][cb * 16 + lane] = s1[cb]; bl2[wid][cb * 16 + lane] = s2[cb]; }
    }
    __syncthreads();
    if (tid < 64) {
        float a  = bl1[0][tid] + bl1[1][tid] + bl1[2][tid] + bl1[3][tid];
        float c2 = bl2[0][tid] + bl2[1][tid] + bl2[2][tid] + bl2[3][tid];
        int sl = bid & (NSLICE - 1);
        atomicAdd(&bns[sl * 128 + tid], a);
        atomicAdd(&bns[sl * 128 + 64 + tid], c2);
    }
}

// ============ ab body (device): A = bn(h)@WA + cA, B = bn(h)@WB + cB (both f16) ============
__device__ __forceinline__ void ab_body(int bid, int tid,
                                        const unsigned short* __restrict__ h,
                                        const float* __restrict__ bns,
                                        const float* __restrict__ g,
                                        const float* __restrict__ bb,
                                        const float* __restrict__ w1,
                                        const float* __restrict__ b1,
                                        unsigned short* __restrict__ A,
                                        unsigned short* __restrict__ Bb,
                                        float* scale, float* shift, float* cab) {
    int lane = tid & 63, wid = tid >> 6;
    int q = lane >> 4, cl = lane & 15, kq = q * 8;

    if (tid < 64) {
        float s1v = 0.f, s2v = 0.f;
#pragma unroll
        for (int s = 0; s < NSLICE; s++) { s1v += bns[s * 128 + tid]; s2v += bns[s * 128 + 64 + tid]; }
        float mu  = s1v * (1.0f / N_NODES);
        float var = s2v * (1.0f / N_NODES) - mu * mu;
        float sc  = g[tid] * rsqrtf(var + EPS);
        scale[tid] = sc;
        shift[tid] = bb[tid] - mu * sc;
    }
    __syncthreads();
    if (tid < 128) {
        int j = tid & 63;
        float acc = (tid < 64) ? b1[j] : 0.f;
        for (int k = 0; k < 64; k++) {
            float wa_ = w1[k * EF + j], wb_ = w1[(64 + k) * EF + j];
            acc = fmaf(shift[k], (tid < 64) ? (wa_ - wb_) : wb_, acc);
        }
        cab[tid] = acc;
    }
    Uh wa[2][4], wb[2][4];
#pragma unroll
    for (int kh = 0; kh < 2; kh++)
#pragma unroll
        for (int cb = 0; cb < 4; cb++)
#pragma unroll
            for (int j = 0; j < 4; j++) {
                int k0 = kh * 32 + kq + 2 * j;
                int col = cb * 16 + cl;
                float sa = scale[k0], sb = scale[k0 + 1];
                float a0 = w1[k0 * EF + col], b0 = w1[(64 + k0) * EF + col];
                float a1 = w1[(k0 + 1) * EF + col], b1v = w1[(64 + k0 + 1) * EF + col];
                wa[kh][cb].h[j] = pk2(sa * (a0 - b0), sb * (a1 - b1v));
                wb[kh][cb].h[j] = pk2(sa * b0, sb * b1v);
            }
    __syncthreads();
    float cav[4], cbv[4];
#pragma unroll
    for (int cb = 0; cb < 4; cb++) { cav[cb] = cab[cb * 16 + cl]; cbv[cb] = cab[64 + cb * 16 + cl]; }

    for (int t = bid * 4 + wid; t < N_TILES; t += NFC0 * 4) {
        int nb = t * 16;
        const unsigned short* hrow = h + (size_t)(nb + cl) * 64 + kq;
        Uh h0f, h1f;
        h0f.v = *(const uintx4*)hrow;
        h1f.v = *(const uintx4*)(hrow + 32);
        floatx4 accA[4] = {{0,0,0,0},{0,0,0,0},{0,0,0,0},{0,0,0,0}};
        floatx4 accB[4] = {{0,0,0,0},{0,0,0,0},{0,0,0,0},{0,0,0,0}};
#pragma unroll
        for (int cb = 0; cb < 4; cb++) {
            accA[cb] = __builtin_amdgcn_mfma_f32_16x16x32_f16(h0f.h8, wa[0][cb].h8, accA[cb], 0, 0, 0);
            accB[cb] = __builtin_amdgcn_mfma_f32_16x16x32_f16(h0f.h8, wb[0][cb].h8, accB[cb], 0, 0, 0);
            accA[cb] = __builtin_amdgcn_mfma_f32_16x16x32_f16(h1f.h8, wa[1][cb].h8, accA[cb], 0, 0, 0);
            accB[cb] = __builtin_amdgcn_mfma_f32_16x16x32_f16(h1f.h8, wb[1][cb].h8, accB[cb], 0, 0, 0);
        }
#pragma unroll
        for (int cb = 0; cb < 4; cb++)
#pragma unroll
            for (int r = 0; r < 4; r++) {
                size_t o = (size_t)(nb + q * 4 + r) * 64 + cb * 16 + cl;
                A[o]  = f2h(accA[cb][r] + cav[cb]);
                Bb[o] = f2h(accB[cb][r] + cbv[cb]);
            }
    }
}

// ==== FUSED: sort-finish (blocks 0..NB-1: hist+scan+ticket+scatter+fill per bucket) + ab0 ====
// Entire bucket handled by ONE block: cnt is a plain write, scatter is block-local LDS cursors.
__global__ __launch_bounds__(256, 4) void sort2_ab_kernel(
        const unsigned* __restrict__ keys, const int* __restrict__ bcnt,
        int* __restrict__ cnt, int* __restrict__ gtotal,
        int* __restrict__ row_start, unsigned short* __restrict__ sorted_src,
        const unsigned short* __restrict__ h, const float* __restrict__ bns,
        const float* __restrict__ g, const float* __restrict__ bb,
        const float* __restrict__ w1, const float* __restrict__ b1,
        unsigned short* __restrict__ A, unsigned short* __restrict__ Bb) {
    __shared__ int lc[256], loc[256], rs[256], cur[256];
    __shared__ int base;
    __shared__ float scale[64], shift[64], cab[128];
    int tid = threadIdx.x;
    if (blockIdx.x < NB) {
        int b = blockIdx.x;
        lc[tid] = 0;
        cur[tid] = 0;
        __syncthreads();
        int beg = b * CAPB, end = beg + bcnt[b];
        const unsigned* kb = keys + beg;
        int nk = end - beg;
        for (int p = tid; p < nk; p += 256)
            atomicAdd(&lc[(kb[p] >> 16) & 255], 1);
        __syncthreads();
        int node = b * 256 + tid;
        int c = lc[tid];
        if (node < N_NODES) cnt[node] = c;          // plain write — no global atomics
        int pc = (c + 15) & ~15;
        loc[tid] = pc;
        __syncthreads();
        for (int off = 1; off < 256; off <<= 1) {
            int t = (tid >= off) ? loc[tid - off] : 0;
            __syncthreads();
            loc[tid] += t;
            __syncthreads();
        }
        if (tid == 255) base = atomicAdd(gtotal, loc[255]);   // ticket: order-free CSR
        __syncthreads();
        int myrs = base + loc[tid] - pc;
        rs[tid] = myrs;
        if (node < N_NODES) row_start[node] = myrs;
        __syncthreads();
        for (int p = tid; p < nk; p += 256) {
            unsigned k = kb[p];
            int lidx = (k >> 16) & 255;
            int r = atomicAdd(&cur[lidx], 1);
            sorted_src[rs[lidx] + r] = (unsigned short)(k & 0xFFFFu);
        }
        __syncthreads();
        if (node < N_NODES && c > 0) {
            unsigned short s0 = sorted_src[myrs];
            int pe = myrs + pc;
            for (int p = myrs + c; p < pe; p++) sorted_src[p] = s0;  // max idempotent
        }
        return;
    }
    ab_body(blockIdx.x - NB, tid, h, bns, g, bb, w1, b1, A, Bb, scale, shift, cab);
}

// ============ plain ab kernel (blocks 1 and 2) ============
__global__ __launch_bounds__(256, 4) void ab_mfma_kernel(
        const unsigned short* __restrict__ h, const float* __restrict__ bns,
        const float* __restrict__ g, const float* __restrict__ bb,
        const float* __restrict__ w1, const float* __restrict__ b1,
        unsigned short* __restrict__ A, unsigned short* __restrict__ Bb) {
    __shared__ float scale[64], shift[64], cab[128];
    ab_body(blockIdx.x, threadIdx.x, h, bns, g, bb, w1, b1, A, Bb, scale, shift, cab);
}

// ============ EdgeConv via f16 MFMA (R10-proven): single node/wave, 2-tile ILP ============
// (256,4): VGPR ~60 -> 8 waves/SIMD. R12: 2-node interleave (76 VGPR, 6 waves) regressed —
// TLP beats intra-wave ILP for this latency-bound gather loop. Ends from cnt[n] (ticket CSR).
__global__ __launch_bounds__(256, 4) void edge_mfma_kernel(
        const unsigned short* __restrict__ A, const unsigned short* __restrict__ Bb,
        const int* __restrict__ row_start, const int* __restrict__ cnt,
        const unsigned short* __restrict__ sorted_src,
        const float* __restrict__ w2, const float* __restrict__ b2,
        unsigned short* __restrict__ catp, float* __restrict__ bnsNext) {
    __shared__ float r1[4][64], r2[4][64];
    int tid = threadIdx.x, lane = tid & 63, wid = tid >> 6;
    int kq = (lane >> 4) * 8;
    int cl = lane & 15;

    Uh bfr[2][4];
#pragma unroll
    for (int kh = 0; kh < 2; kh++)
#pragma unroll
        for (int cb = 0; cb < 4; cb++)
#pragma unroll
            for (int j = 0; j < 4; j++) {
                _Float16 w0 = (_Float16)w2[(kh * 32 + kq + 2 * j) * 64 + cb * 16 + cl];
                _Float16 w1 = (_Float16)w2[(kh * 32 + kq + 2 * j + 1) * 64 + cb * 16 + cl];
                bfr[kh][cb].h[j] = half2v{w0, w1};
            }
    float b2j = b2[lane];
    float s1 = 0.f, s2 = 0.f;
    const half2v zeroh = {(_Float16)0.f, (_Float16)0.f};

    for (int n = blockIdx.x * 4 + wid; n < N_NODES; n += gridDim.x * 4) {
        int beg = row_start[n];
        int end = beg + ((cnt[n] + 15) & ~15);
        const unsigned short* arow = A + (size_t)n * 64 + kq;
        Uh a0u, a1u;
        a0u.v = *(const uintx4*)(arow);
        a1u.v = *(const uintx4*)(arow + 32);
        floatx4 rmax0 = {-INFINITY, -INFINITY, -INFINITY, -INFINITY};
        floatx4 rmax1 = rmax0, rmax2 = rmax0, rmax3 = rmax0;

        auto tile = [&](uintx4 u0, uintx4 u1) {
            Uh b0u, b1u, f0, f1;
            b0u.v = u0; b1u.v = u1;
#pragma unroll
            for (int j = 0; j < 4; j++) {      // v_pk_add_f16 + v_pk_max_f16
                f0.h[j] = __builtin_elementwise_max(a0u.h[j] + b0u.h[j], zeroh);
                f1.h[j] = __builtin_elementwise_max(a1u.h[j] + b1u.h[j], zeroh);
            }
            floatx4 acc0 = {0.f, 0.f, 0.f, 0.f}, acc1 = acc0, acc2 = acc0, acc3 = acc0;
            acc0 = __builtin_amdgcn_mfma_f32_16x16x32_f16(f0.h8, bfr[0][0].h8, acc0, 0, 0, 0);
            acc1 = __builtin_amdgcn_mfma_f32_16x16x32_f16(f0.h8, bfr[0][1].h8, acc1, 0, 0, 0);
            acc2 = __builtin_amdgcn_mfma_f32_16x16x32_f16(f0.h8, bfr[0][2].h8, acc2, 0, 0, 0);
            acc3 = __builtin_amdgcn_mfma_f32_16x16x32_f16(f0.h8, bfr[0][3].h8, acc3, 0, 0, 0);
            acc0 = __builtin_amdgcn_mfma_f32_16x16x32_f16(f1.h8, bfr[1][0].h8, acc0, 0, 0, 0);
            acc1 = __builtin_amdgcn_mfma_f32_16x16x32_f16(f1.h8, bfr[1][1].h8, acc1, 0, 0, 0);
            acc2 = __builtin_amdgcn_mfma_f32_16x16x32_f16(f1.h8, bfr[1][2].h8, acc2, 0, 0, 0);
            acc3 = __builtin_amdgcn_mfma_f32_16x16x32_f16(f1.h8, bfr[1][3].h8, acc3, 0, 0, 0);
            rmax0 = __builtin_elementwise_max(rmax0, acc0);
            rmax1 = __builtin_elementwise_max(rmax1, acc1);
            rmax2 = __builtin_elementwise_max(rmax2, acc2);
            rmax3 = __builtin_elementwise_max(rmax3, acc3);
        };
        auto gather = [&](int p, uintx4& u0, uintx4& u1) {
            int srcm = sorted_src[p + cl];
            const unsigned short* brow = Bb + (size_t)srcm * 64 + kq;
            u0 = *(const uintx4*)(brow);
            u1 = *(const uintx4*)(brow + 32);
        };

        int p0 = beg;
        for (; p0 + 32 <= end; p0 += 32) {   // two tiles per iter: both gathers in flight
            uintx4 x0, x1, y0, y1;
            gather(p0, x0, x1);
            gather(p0 + 16, y0, y1);
            tile(x0, x1);
            tile(y0, y1);
        }
        if (p0 < end) {                       // odd-tile remainder
            uintx4 x0, x1;
            gather(p0, x0, x1);
            tile(x0, x1);
        }

        float v0 = fmaxf(fmaxf(rmax0.x, rmax0.y), fmaxf(rmax0.z, rmax0.w));
        float v1 = fmaxf(fmaxf(rmax1.x, rmax1.y), fmaxf(rmax1.z, rmax1.w));
        float v2 = fmaxf(fmaxf(rmax2.x, rmax2.y), fmaxf(rmax2.z, rmax2.w));
        float v3 = fmaxf(fmaxf(rmax3.x, rmax3.y), fmaxf(rmax3.z, rmax3.w));
        v0 = fmaxf(v0, __shfl_xor(v0, 16)); v0 = fmaxf(v0, __shfl_xor(v0, 32));
        v1 = fmaxf(v1, __shfl_xor(v1, 16)); v1 = fmaxf(v1, __shfl_xor(v1, 32));
        v2 = fmaxf(v2, __shfl_xor(v2, 16)); v2 = fmaxf(v2, __shfl_xor(v2, 32));
        v3 = fmaxf(v3, __shfl_xor(v3, 16)); v3 = fmaxf(v3, __shfl_xor(v3, 32));
        float vs = (lane & 32) ? ((lane & 16) ? v3 : v2) : ((lane & 16) ? v1 : v0);
        float v = fmaxf(vs + b2j, 0.f);  // -inf (empty node) -> 0; folds where(isfinite)+relu
        catp[(size_t)n * 64 + lane] = f2h(v);
        s1 += v; s2 += v * v;
    }

    if (bnsNext) {
        r1[wid][lane] = s1; r2[wid][lane] = s2;
        __syncthreads();
        if (tid < 64) {
            float a  = r1[0][tid] + r1[1][tid] + r1[2][tid] + r1[3][tid];
            float c2 = r2[0][tid] + r2[1][tid] + r2[2][tid] + r2[3][tid];
            int sl = blockIdx.x & (NSLICE - 1);
            atomicAdd(&bnsNext[sl * 128 + tid], a);
            atomicAdd(&bnsNext[sl * 128 + 64 + tid], c2);
        }
    }
}

// ============================ fused graph mean pool + MLP head + log_softmax ============================
__global__ __launch_bounds__(192) void poolhead_kernel(const unsigned short* __restrict__ cat0,
                                                       const unsigned short* __restrict__ cat1,
                                                       const unsigned short* __restrict__ cat2,
                                                       const int* __restrict__ batch,
                                                       const float* __restrict__ fc1w,
                                                       const float* __restrict__ fc1b,
                                                       const float* __restrict__ fc2w,
                                                       const float* __restrict__ fc2b,
                                                       float* __restrict__ out) {
    __shared__ int se[2];
    __shared__ float p[192];
    __shared__ float hid[128];
    __shared__ float z[10];
    __shared__ float lse;
    int g = blockIdx.x, tid = threadIdx.x;  // 192 threads
    if (tid < 2) {
        int target = g + tid;
        int lo = 0, hi = N_NODES;
        while (lo < hi) { int mid = (lo + hi) >> 1; if (batch[mid] < target) lo = mid + 1; else hi = mid; }
        se[tid] = lo;
    }
    __syncthreads();
    int s = se[0], e = se[1];
    const unsigned short* plane = (tid < 64) ? cat0 : ((tid < 128) ? cat1 : cat2);
    int col = tid & 63;
    float a0 = 0.f, a1 = 0.f, a2 = 0.f, a3 = 0.f;   // 4-way ILP in the pooling loop
    int r = s;
    for (; r + 4 <= e; r += 4) {
        a0 += h2f(plane[(size_t)(r + 0) * 64 + col]);
        a1 += h2f(plane[(size_t)(r + 1) * 64 + col]);
        a2 += h2f(plane[(size_t)(r + 2) * 64 + col]);
        a3 += h2f(plane[(size_t)(r + 3) * 64 + col]);
    }
    for (; r < e; r++) a0 += h2f(plane[(size_t)r * 64 + col]);
    float acc = (a0 + a1) + (a2 + a3);
    float denom = (e > s) ? (float)(e - s) : 1.0f;
    p[tid] = acc / denom;
    __syncthreads();
    if (tid < MLP_DIM) {
        float a = fc1b[tid];
        for (int k = 0; k < 192; k++) a = fmaf(p[k], fc1w[k * 128 + tid], a);
        hid[tid] = fmaxf(a, 0.f);
    }
    __syncthreads();
    if (tid < N_CLASSES) {
        float a = fc2b[tid];
        for (int k = 0; k < 128; k++) a = fmaf(hid[k], fc2w[k * 10 + tid], a);
        z[tid] = a;
    }
    __syncthreads();
    if (tid == 0) {
        float m = z[0];
        for (int i = 1; i < 10; i++) m = fmaxf(m, z[i]);
        float sm = 0.f;
        for (int i = 0; i < 10; i++) sm += expf(z[i] - m);
        lse = m + logf(sm);
    }
    __syncthreads();
    if (tid < N_CLASSES) out[g * 10 + tid] = z[tid] - lse;
}

// ============================ launch ============================
extern "C" void kernel_launch(void* const* d_in, const int* in_sizes, int n_in,
                              void* d_out, int out_size, void* d_ws, size_t ws_size,
                              hipStream_t stream) {
    (void)in_sizes; (void)n_in; (void)out_size; (void)ws_size;
    const float* x    = (const float*)d_in[0];
    const int*   ei   = (const int*)d_in[1];
    const int*   batch= (const int*)d_in[2];
    const float* fc0w = (const float*)d_in[3];
    const float* fc0b = (const float*)d_in[4];
    const float* fc1w = (const float*)d_in[5];
    const float* fc1b = (const float*)d_in[6];
    const float* fc2w = (const float*)d_in[7];
    const float* fc2b = (const float*)d_in[8];
    const int* src = ei;
    const int* dst = ei + N_EDGES;
    float* out = (float*)d_out;

    char* w = (char*)d_ws;
    size_t off = 0;
    auto alloc = [&](size_t bytes) -> void* {
        void* p = w + off;
        off = (off + bytes + 255) & ~(size_t)255;
        return p;
    };
    const size_t MAX_PAD_EDGES = (size_t)N_EDGES + 16 * (size_t)N_NODES;

    // zeroed-every-launch block: gcur[NB] | gtotal | bns[3][NSLICE][128]
    const size_t BNS_OFF = 1280;
    const size_t ZBYTES  = BNS_OFF + 3 * NSLICE * 128 * 4;
    char* zbase = (char*)alloc(ZBYTES);
    int*   gcur   = (int*)zbase;                     // NB ints (bucket cursors = final counts)
    int*   gtotal = (int*)(zbase + 1024);            // sort2 ticket
    float* bnsAll = (float*)(zbase + BNS_OFF);       // 3 * NSLICE * 128 floats

    unsigned short* cat0 = (unsigned short*)alloc((size_t)N_NODES * 64 * 2);  // 6.4 MB/plane (f16)
    unsigned short* cat1 = (unsigned short*)alloc((size_t)N_NODES * 64 * 2);
    unsigned short* cat2 = (unsigned short*)alloc((size_t)N_NODES * 64 * 2);
    unsigned short* h0   = (unsigned short*)alloc((size_t)N_NODES * 64 * 2);
    unsigned short* Ae   = (unsigned short*)alloc((size_t)N_NODES * 64 * 2);
    unsigned short* Be   = (unsigned short*)alloc((size_t)N_NODES * 64 * 2);
    unsigned* keys = (unsigned*)alloc((size_t)NB * CAPB * 4);    // 12.85 MB
    unsigned short* sorted_src = (unsigned short*)alloc(MAX_PAD_EDGES * 2);  // 4.8 MB
    int*   cnt       = (int*)alloc((size_t)N_NODES * 4);   // plain-written in sort2
    int*   row_start = (int*)alloc((size_t)N_NODES * 4);

    (void)hipMemsetAsync(zbase, 0, ZBYTES, stream);

    // D1: pass1 + fc0 fused (independent; pass1 hides under fc0)
    fc0_pass1_kernel<<<NPASS1 + NFC0, 256, 0, stream>>>(src, dst, gcur, keys,
                                                        x, fc0w, fc0b, h0, bnsAll);
    // D2: sort-finish (hist+scan+ticket+scatter+fill) + ab(block 0) fused
    sort2_ab_kernel<<<NB + NFC0, 256, 0, stream>>>(
        keys, gcur, cnt, gtotal, row_start, sorted_src,
        h0, bnsAll,
        (const float*)d_in[9], (const float*)d_in[10],
        (const float*)d_in[11], (const float*)d_in[12], Ae, Be);

    unsigned short* planes[3] = {cat0, cat1, cat2};
    for (int blk = 0; blk < 3; blk++) {
        const float* w2 = (const float*)d_in[13 + 6 * blk];
        const float* b2 = (const float*)d_in[14 + 6 * blk];
        if (blk > 0) {
            ab_mfma_kernel<<<NFC0, 256, 0, stream>>>(
                planes[blk - 1], bnsAll + blk * NSLICE * 128,
                (const float*)d_in[9 + 6 * blk], (const float*)d_in[10 + 6 * blk],
                (const float*)d_in[11 + 6 * blk], (const float*)d_in[12 + 6 * blk], Ae, Be);
        }
        edge_mfma_kernel<<<4096, 256, 0, stream>>>(
            Ae, Be, row_start, cnt, sorted_src, w2, b2, planes[blk],
            (blk < 2) ? (bnsAll + (blk + 1) * NSLICE * 128) : nullptr);
    }

    poolhead_kernel<<<N_GRAPHS, 192, 0, stream>>>(cat0, cat1, cat2, batch,
                                                  fc1w, fc1b, fc2w, fc2b, out);
}

// Round 16
// 375.254 us; speedup vs baseline: 1.4542x; 1.0416x over previous
//
#include <hip/hip_runtime.h>
#include <math.h>

#define N_NODES 50000
#define N_TILES 3125      // N_NODES / 16 exactly
#define N_EDGES 1600000
#define F_IN 128
#define C 64
#define EF 64
#define N_GRAPHS 512
#define MLP_DIM 128
#define N_CLASSES 10
#define EPS 1e-5f
#define NB 196            // coarse buckets: dst>>8, 256 nodes each
#define CAPB 16384        // fixed bucket capacity (mean 8192, std ~90 -> safe)
#define CHUNK 4096        // edges per pass-1 block
#define NPASS1 391        // ceil(N_EDGES / CHUNK)
#define NFC0 782          // fc0 / ab MFMA blocks
#define NSLICE 8          // bn-stat atomic slices

typedef __attribute__((ext_vector_type(8))) _Float16 half8;
typedef __attribute__((ext_vector_type(2))) _Float16 half2v;
typedef __attribute__((ext_vector_type(4))) float floatx4;
typedef __attribute__((ext_vector_type(4))) unsigned uintx4;

union Uh { uintx4 v; half2v h[4]; half8 h8; };

__device__ __forceinline__ unsigned short f2h(float a) {
    union { _Float16 f; unsigned short u; } c;
    c.f = (_Float16)a;   // RNE
    return c.u;
}
__device__ __forceinline__ float h2f(unsigned short u) {
    union { unsigned short u; _Float16 f; } c;
    c.u = u;
    return (float)c.f;
}
__device__ __forceinline__ half2v pk2(float a, float b) {
    auto t = __builtin_amdgcn_cvt_pkrtz(a, b);   // __fp16 vec2 -> bit-cast (R6 lesson)
    union { decltype(t) i; half2v o; } c;
    c.i = t;
    return c.o;
}

// ============ FUSED: pass1 (blocks 0..NPASS1-1) + fc0 MFMA (blocks NPASS1..) ============
// Independent stages share one dispatch; pass1's latency hides under fc0's MFMA work.
// NO per-node global atomics in pass1 — R11: 1.6M random atomicAdds cost 57 MB cross-XCD writeback.
__global__ __launch_bounds__(256, 3) void fc0_pass1_kernel(
        const int* __restrict__ src, const int* __restrict__ dst,
        int* __restrict__ gcur, unsigned* __restrict__ keys,
        const float* __restrict__ x, const float* __restrict__ w,
        const float* __restrict__ b, unsigned short* __restrict__ h0,
        float* __restrict__ bns) {
    __shared__ int lcnt[NB], lbase[NB], lcnt2[NB];
    __shared__ float bl1[4][64], bl2[4][64];
    int tid = threadIdx.x;

    if (blockIdx.x < NPASS1) {
        // ---------------- pass1: bin edges into fixed-capacity buckets ----------------
        int e0 = blockIdx.x * CHUNK;
        unsigned k[CHUNK / 256];
        int bk[CHUNK / 256];
        for (int i = tid; i < NB; i += 256) lcnt[i] = 0;
        __syncthreads();
#pragma unroll
        for (int i = 0; i < CHUNK / 256; i++) {
            int e = e0 + i * 256 + tid;
            if (e < N_EDGES) {
                int d = dst[e];
                k[i] = ((unsigned)d << 16) | (unsigned)src[e];
                bk[i] = d >> 8;
                atomicAdd(&lcnt[bk[i]], 1);
            } else bk[i] = -1;
        }
        __syncthreads();
        for (int i = tid; i < NB; i += 256) {
            int c = lcnt[i];
            lbase[i] = c ? atomicAdd(&gcur[i], c) : 0;
            lcnt2[i] = 0;
        }
        __syncthreads();
#pragma unroll
        for (int i = 0; i < CHUNK / 256; i++) {
            if (bk[i] >= 0) {
                int r = atomicAdd(&lcnt2[bk[i]], 1);
                keys[(size_t)bk[i] * CAPB + lbase[bk[i]] + r] = k[i];
            }
        }
        return;
    }

    // ---------------- fc0: h0[16-node tile] = x @ fc0_w + b (f16) + BN stats ----------------
    int bid = blockIdx.x - NPASS1;
    int lane = tid & 63, wid = tid >> 6;
    int q = lane >> 4, cl = lane & 15, kq = q * 8;

    Uh wf[4][4];
#pragma unroll
    for (int kh = 0; kh < 4; kh++)
#pragma unroll
        for (int cb = 0; cb < 4; cb++)
#pragma unroll
            for (int j = 0; j < 4; j++) {
                int k0 = kh * 32 + kq + 2 * j;
                int col = cb * 16 + cl;
                wf[kh][cb].h[j] = pk2(w[k0 * 64 + col], w[(k0 + 1) * 64 + col]);
            }
    float bv[4];
#pragma unroll
    for (int cb = 0; cb < 4; cb++) bv[cb] = b[cb * 16 + cl];
    float s1[4] = {0, 0, 0, 0}, s2[4] = {0, 0, 0, 0};

    for (int t = bid * 4 + wid; t < N_TILES; t += NFC0 * 4) {
        int nb = t * 16;
        floatx4 acc[4] = {{0,0,0,0},{0,0,0,0},{0,0,0,0},{0,0,0,0}};
#pragma unroll
        for (int kh = 0; kh < 4; kh++) {
            const float* xr = x + (size_t)(nb + cl) * F_IN + kh * 32 + kq;
            floatx4 xa = *(const floatx4*)xr;
            floatx4 xb = *(const floatx4*)(xr + 4);
            Uh xf;
            xf.h[0] = pk2(xa.x, xa.y); xf.h[1] = pk2(xa.z, xa.w);
            xf.h[2] = pk2(xb.x, xb.y); xf.h[3] = pk2(xb.z, xb.w);
#pragma unroll
            for (int cb = 0; cb < 4; cb++)
                acc[cb] = __builtin_amdgcn_mfma_f32_16x16x32_f16(xf.h8, wf[kh][cb].h8, acc[cb], 0, 0, 0);
        }
#pragma unroll
        for (int cb = 0; cb < 4; cb++)
#pragma unroll
            for (int r = 0; r < 4; r++) {
                float v = acc[cb][r] + bv[cb];            // node = nb+q*4+r, col = cb*16+cl
                h0[(size_t)(nb + q * 4 + r) * 64 + cb * 16 + cl] = f2h(v);
                s1[cb] += v; s2[cb] += v * v;
            }
    }
#pragma unroll
    for (int cb = 0; cb < 4; cb++) {
        s1[cb] += __shfl_xor(s1[cb], 16); s1[cb] += __shfl_xor(s1[cb], 32);
        s2[cb] += __shfl_xor(s2[cb], 16); s2[cb] += __shfl_xor(s2[cb], 32);
    }
    if (lane < 16) {
#pragma unroll
        for (int cb = 0; cb < 4; cb++) { bl1[wid][cb * 16 + lane] = s1[cb]; bl2[wid][cb * 16 + lane] = s2[cb]; }
    }
    __syncthreads();
    if (tid < 64) {
        float a  = bl1[0][tid] + bl1[1][tid] + bl1[2][tid] + bl1[3][tid];
        float c2 = bl2[0][tid] + bl2[1][tid] + bl2[2][tid] + bl2[3][tid];
        int sl = bid & (NSLICE - 1);
        atomicAdd(&bns[sl * 128 + tid], a);
        atomicAdd(&bns[sl * 128 + 64 + tid], c2);
    }
}

// ============ ab body (device): A = bn(h)@WA + cA, B = bn(h)@WB + cB (both f16) ============
__device__ __forceinline__ void ab_body(int bid, int tid,
                                        const unsigned short* __restrict__ h,
                                        const float* __restrict__ bns,
                                        const float* __restrict__ g,
                                        const float* __restrict__ bb,
                                        const float* __restrict__ w1,
                                        const float* __restrict__ b1,
                                        unsigned short* __restrict__ A,
                                        unsigned short* __restrict__ Bb,
                                        float* scale, float* shift, float* cab) {
    int lane = tid & 63, wid = tid >> 6;
    int q = lane >> 4, cl = lane & 15, kq = q * 8;

    if (tid < 64) {
        float s1v = 0.f, s2v = 0.f;
#pragma unroll
        for (int s = 0; s < NSLICE; s++) { s1v += bns[s * 128 + tid]; s2v += bns[s * 128 + 64 + tid]; }
        float mu  = s1v * (1.0f / N_NODES);
        float var = s2v * (1.0f / N_NODES) - mu * mu;
        float sc  = g[tid] * rsqrtf(var + EPS);
        scale[tid] = sc;
        shift[tid] = bb[tid] - mu * sc;
    }
    __syncthreads();
    if (tid < 128) {
        int j = tid & 63;
        float acc = (tid < 64) ? b1[j] : 0.f;
        for (int k = 0; k < 64; k++) {
            float wa_ = w1[k * EF + j], wb_ = w1[(64 + k) * EF + j];
            acc = fmaf(shift[k], (tid < 64) ? (wa_ - wb_) : wb_, acc);
        }
        cab[tid] = acc;
    }
    Uh wa[2][4], wb[2][4];
#pragma unroll
    for (int kh = 0; kh < 2; kh++)
#pragma unroll
        for (int cb = 0; cb < 4; cb++)
#pragma unroll
            for (int j = 0; j < 4; j++) {
                int k0 = kh * 32 + kq + 2 * j;
                int col = cb * 16 + cl;
                float sa = scale[k0], sb = scale[k0 + 1];
                float a0 = w1[k0 * EF + col], b0 = w1[(64 + k0) * EF + col];
                float a1 = w1[(k0 + 1) * EF + col], b1v = w1[(64 + k0 + 1) * EF + col];
                wa[kh][cb].h[j] = pk2(sa * (a0 - b0), sb * (a1 - b1v));
                wb[kh][cb].h[j] = pk2(sa * b0, sb * b1v);
            }
    __syncthreads();
    float cav[4], cbv[4];
#pragma unroll
    for (int cb = 0; cb < 4; cb++) { cav[cb] = cab[cb * 16 + cl]; cbv[cb] = cab[64 + cb * 16 + cl]; }

    for (int t = bid * 4 + wid; t < N_TILES; t += NFC0 * 4) {
        int nb = t * 16;
        const unsigned short* hrow = h + (size_t)(nb + cl) * 64 + kq;
        Uh h0f, h1f;
        h0f.v = *(const uintx4*)hrow;
        h1f.v = *(const uintx4*)(hrow + 32);
        floatx4 accA[4] = {{0,0,0,0},{0,0,0,0},{0,0,0,0},{0,0,0,0}};
        floatx4 accB[4] = {{0,0,0,0},{0,0,0,0},{0,0,0,0},{0,0,0,0}};
#pragma unroll
        for (int cb = 0; cb < 4; cb++) {
            accA[cb] = __builtin_amdgcn_mfma_f32_16x16x32_f16(h0f.h8, wa[0][cb].h8, accA[cb], 0, 0, 0);
            accB[cb] = __builtin_amdgcn_mfma_f32_16x16x32_f16(h0f.h8, wb[0][cb].h8, accB[cb], 0, 0, 0);
            accA[cb] = __builtin_amdgcn_mfma_f32_16x16x32_f16(h1f.h8, wa[1][cb].h8, accA[cb], 0, 0, 0);
            accB[cb] = __builtin_amdgcn_mfma_f32_16x16x32_f16(h1f.h8, wb[1][cb].h8, accB[cb], 0, 0, 0);
        }
#pragma unroll
        for (int cb = 0; cb < 4; cb++)
#pragma unroll
            for (int r = 0; r < 4; r++) {
                size_t o = (size_t)(nb + q * 4 + r) * 64 + cb * 16 + cl;
                A[o]  = f2h(accA[cb][r] + cav[cb]);
                Bb[o] = f2h(accB[cb][r] + cbv[cb]);
            }
    }
}

// ==== FUSED: sort-finish (blocks 0..NB-1: hist+scan+ticket+scatter+fill per bucket) + ab0 ====
// Entire bucket handled by ONE block: cnt is a plain write, scatter is block-local LDS cursors.
__global__ __launch_bounds__(256, 4) void sort2_ab_kernel(
        const unsigned* __restrict__ keys, const int* __restrict__ bcnt,
        int* __restrict__ cnt, int* __restrict__ gtotal,
        int* __restrict__ row_start, unsigned short* __restrict__ sorted_src,
        const unsigned short* __restrict__ h, const float* __restrict__ bns,
        const float* __restrict__ g, const float* __restrict__ bb,
        const float* __restrict__ w1, const float* __restrict__ b1,
        unsigned short* __restrict__ A, unsigned short* __restrict__ Bb) {
    __shared__ int lc[256], loc[256], rs[256], cur[256];
    __shared__ int base;
    __shared__ float scale[64], shift[64], cab[128];
    int tid = threadIdx.x;
    if (blockIdx.x < NB) {
        int b = blockIdx.x;
        lc[tid] = 0;
        cur[tid] = 0;
        __syncthreads();
        int beg = b * CAPB, end = beg + bcnt[b];
        const unsigned* kb = keys + beg;
        int nk = end - beg;
        for (int p = tid; p < nk; p += 256)
            atomicAdd(&lc[(kb[p] >> 16) & 255], 1);
        __syncthreads();
        int node = b * 256 + tid;
        int c = lc[tid];
        if (node < N_NODES) cnt[node] = c;          // plain write — no global atomics
        int pc = (c + 15) & ~15;
        loc[tid] = pc;
        __syncthreads();
        for (int off = 1; off < 256; off <<= 1) {
            int t = (tid >= off) ? loc[tid - off] : 0;
            __syncthreads();
            loc[tid] += t;
            __syncthreads();
        }
        if (tid == 255) base = atomicAdd(gtotal, loc[255]);   // ticket: order-free CSR
        __syncthreads();
        int myrs = base + loc[tid] - pc;
        rs[tid] = myrs;
        if (node < N_NODES) row_start[node] = myrs;
        __syncthreads();
        for (int p = tid; p < nk; p += 256) {
            unsigned k = kb[p];
            int lidx = (k >> 16) & 255;
            int r = atomicAdd(&cur[lidx], 1);
            sorted_src[rs[lidx] + r] = (unsigned short)(k & 0xFFFFu);
        }
        __syncthreads();
        if (node < N_NODES && c > 0) {
            unsigned short s0 = sorted_src[myrs];
            int pe = myrs + pc;
            for (int p = myrs + c; p < pe; p++) sorted_src[p] = s0;  // max idempotent
        }
        return;
    }
    ab_body(blockIdx.x - NB, tid, h, bns, g, bb, w1, b1, A, Bb, scale, shift, cab);
}

// ============ plain ab kernel (blocks 1 and 2) ============
__global__ __launch_bounds__(256, 4) void ab_mfma_kernel(
        const unsigned short* __restrict__ h, const float* __restrict__ bns,
        const float* __restrict__ g, const float* __restrict__ bb,
        const float* __restrict__ w1, const float* __restrict__ b1,
        unsigned short* __restrict__ A, unsigned short* __restrict__ Bb) {
    __shared__ float scale[64], shift[64], cab[128];
    ab_body(blockIdx.x, threadIdx.x, h, bns, g, bb, w1, b1, A, Bb, scale, shift, cab);
}

// ============ EdgeConv via f16 MFMA (R10-proven): single node/wave, 2-tile ILP ============
// Grid 2048 (R15: 4096 regressed 47.4->51.6 µs — prologue amortization beats tail-trimming).
// (256,4): VGPR ~60 -> 8 waves/SIMD. R12: 2-node interleave (76 VGPR, 6 waves) regressed —
// TLP beats intra-wave ILP for this latency-bound gather loop. Ends from cnt[n] (ticket CSR).
__global__ __launch_bounds__(256, 4) void edge_mfma_kernel(
        const unsigned short* __restrict__ A, const unsigned short* __restrict__ Bb,
        const int* __restrict__ row_start, const int* __restrict__ cnt,
        const unsigned short* __restrict__ sorted_src,
        const float* __restrict__ w2, const float* __restrict__ b2,
        unsigned short* __restrict__ catp, float* __restrict__ bnsNext) {
    __shared__ float r1[4][64], r2[4][64];
    int tid = threadIdx.x, lane = tid & 63, wid = tid >> 6;
    int kq = (lane >> 4) * 8;
    int cl = lane & 15;

    Uh bfr[2][4];
#pragma unroll
    for (int kh = 0; kh < 2; kh++)
#pragma unroll
        for (int cb = 0; cb < 4; cb++)
#pragma unroll
            for (int j = 0; j < 4; j++) {
                _Float16 w0 = (_Float16)w2[(kh * 32 + kq + 2 * j) * 64 + cb * 16 + cl];
                _Float16 w1 = (_Float16)w2[(kh * 32 + kq + 2 * j + 1) * 64 + cb * 16 + cl];
                bfr[kh][cb].h[j] = half2v{w0, w1};
            }
    float b2j = b2[lane];
    float s1 = 0.f, s2 = 0.f;
    const half2v zeroh = {(_Float16)0.f, (_Float16)0.f};

    for (int n = blockIdx.x * 4 + wid; n < N_NODES; n += gridDim.x * 4) {
        int beg = row_start[n];
        int end = beg + ((cnt[n] + 15) & ~15);
        const unsigned short* arow = A + (size_t)n * 64 + kq;
        Uh a0u, a1u;
        a0u.v = *(const uintx4*)(arow);
        a1u.v = *(const uintx4*)(arow + 32);
        floatx4 rmax0 = {-INFINITY, -INFINITY, -INFINITY, -INFINITY};
        floatx4 rmax1 = rmax0, rmax2 = rmax0, rmax3 = rmax0;

        auto tile = [&](uintx4 u0, uintx4 u1) {
            Uh b0u, b1u, f0, f1;
            b0u.v = u0; b1u.v = u1;
#pragma unroll
            for (int j = 0; j < 4; j++) {      // v_pk_add_f16 + v_pk_max_f16
                f0.h[j] = __builtin_elementwise_max(a0u.h[j] + b0u.h[j], zeroh);
                f1.h[j] = __builtin_elementwise_max(a1u.h[j] + b1u.h[j], zeroh);
            }
            floatx4 acc0 = {0.f, 0.f, 0.f, 0.f}, acc1 = acc0, acc2 = acc0, acc3 = acc0;
            acc0 = __builtin_amdgcn_mfma_f32_16x16x32_f16(f0.h8, bfr[0][0].h8, acc0, 0, 0, 0);
            acc1 = __builtin_amdgcn_mfma_f32_16x16x32_f16(f0.h8, bfr[0][1].h8, acc1, 0, 0, 0);
            acc2 = __builtin_amdgcn_mfma_f32_16x16x32_f16(f0.h8, bfr[0][2].h8, acc2, 0, 0, 0);
            acc3 = __builtin_amdgcn_mfma_f32_16x16x32_f16(f0.h8, bfr[0][3].h8, acc3, 0, 0, 0);
            acc0 = __builtin_amdgcn_mfma_f32_16x16x32_f16(f1.h8, bfr[1][0].h8, acc0, 0, 0, 0);
            acc1 = __builtin_amdgcn_mfma_f32_16x16x32_f16(f1.h8, bfr[1][1].h8, acc1, 0, 0, 0);
            acc2 = __builtin_amdgcn_mfma_f32_16x16x32_f16(f1.h8, bfr[1][2].h8, acc2, 0, 0, 0);
            acc3 = __builtin_amdgcn_mfma_f32_16x16x32_f16(f1.h8, bfr[1][3].h8, acc3, 0, 0, 0);
            rmax0 = __builtin_elementwise_max(rmax0, acc0);
            rmax1 = __builtin_elementwise_max(rmax1, acc1);
            rmax2 = __builtin_elementwise_max(rmax2, acc2);
            rmax3 = __builtin_elementwise_max(rmax3, acc3);
        };
        auto gather = [&](int p, uintx4& u0, uintx4& u1) {
            int srcm = sorted_src[p + cl];
            const unsigned short* brow = Bb + (size_t)srcm * 64 + kq;
            u0 = *(const uintx4*)(brow);
            u1 = *(const uintx4*)(brow + 32);
        };

        int p0 = beg;
        for (; p0 + 32 <= end; p0 += 32) {   // two tiles per iter: both gathers in flight
            uintx4 x0, x1, y0, y1;
            gather(p0, x0, x1);
            gather(p0 + 16, y0, y1);
            tile(x0, x1);
            tile(y0, y1);
        }
        if (p0 < end) {                       // odd-tile remainder
            uintx4 x0, x1;
            gather(p0, x0, x1);
            tile(x0, x1);
        }

        float v0 = fmaxf(fmaxf(rmax0.x, rmax0.y), fmaxf(rmax0.z, rmax0.w));
        float v1 = fmaxf(fmaxf(rmax1.x, rmax1.y), fmaxf(rmax1.z, rmax1.w));
        float v2 = fmaxf(fmaxf(rmax2.x, rmax2.y), fmaxf(rmax2.z, rmax2.w));
        float v3 = fmaxf(fmaxf(rmax3.x, rmax3.y), fmaxf(rmax3.z, rmax3.w));
        v0 = fmaxf(v0, __shfl_xor(v0, 16)); v0 = fmaxf(v0, __shfl_xor(v0, 32));
        v1 = fmaxf(v1, __shfl_xor(v1, 16)); v1 = fmaxf(v1, __shfl_xor(v1, 32));
        v2 = fmaxf(v2, __shfl_xor(v2, 16)); v2 = fmaxf(v2, __shfl_xor(v2, 32));
        v3 = fmaxf(v3, __shfl_xor(v3, 16)); v3 = fmaxf(v3, __shfl_xor(v3, 32));
        float vs = (lane & 32) ? ((lane & 16) ? v3 : v2) : ((lane & 16) ? v1 : v0);
        float v = fmaxf(vs + b2j, 0.f);  // -inf (empty node) -> 0; folds where(isfinite)+relu
        catp[(size_t)n * 64 + lane] = f2h(v);
        s1 += v; s2 += v * v;
    }

    if (bnsNext) {
        r1[wid][lane] = s1; r2[wid][lane] = s2;
        __syncthreads();
        if (tid < 64) {
            float a  = r1[0][tid] + r1[1][tid] + r1[2][tid] + r1[3][tid];
            float c2 = r2[0][tid] + r2[1][tid] + r2[2][tid] + r2[3][tid];
            int sl = blockIdx.x & (NSLICE - 1);
            atomicAdd(&bnsNext[sl * 128 + tid], a);
            atomicAdd(&bnsNext[sl * 128 + 64 + tid], c2);
        }
    }
}

// ============================ fused graph mean pool + MLP head + log_softmax ============================
__global__ __launch_bounds__(192) void poolhead_kernel(const unsigned short* __restrict__ cat0,
                                                       const unsigned short* __restrict__ cat1,
                                                       const unsigned short* __restrict__ cat2,
                                                       const int* __restrict__ batch,
                                                       const float* __restrict__ fc1w,
                                                       const float* __restrict__ fc1b,
                                                       const float* __restrict__ fc2w,
                                                       const float* __restrict__ fc2b,
                                                       float* __restrict__ out) {
    __shared__ int se[2];
    __shared__ float p[192];
    __shared__ float hid[128];
    __shared__ float z[10];
    __shared__ float lse;
    int g = blockIdx.x, tid = threadIdx.x;  // 192 threads
    if (tid < 2) {
        int target = g + tid;
        int lo = 0, hi = N_NODES;
        while (lo < hi) { int mid = (lo + hi) >> 1; if (batch[mid] < target) lo = mid + 1; else hi = mid; }
        se[tid] = lo;
    }
    __syncthreads();
    int s = se[0], e = se[1];
    const unsigned short* plane = (tid < 64) ? cat0 : ((tid < 128) ? cat1 : cat2);
    int col = tid & 63;
    float a0 = 0.f, a1 = 0.f, a2 = 0.f, a3 = 0.f;   // 4-way ILP in the pooling loop
    int r = s;
    for (; r + 4 <= e; r += 4) {
        a0 += h2f(plane[(size_t)(r + 0) * 64 + col]);
        a1 += h2f(plane[(size_t)(r + 1) * 64 + col]);
        a2 += h2f(plane[(size_t)(r + 2) * 64 + col]);
        a3 += h2f(plane[(size_t)(r + 3) * 64 + col]);
    }
    for (; r < e; r++) a0 += h2f(plane[(size_t)r * 64 + col]);
    float acc = (a0 + a1) + (a2 + a3);
    float denom = (e > s) ? (float)(e - s) : 1.0f;
    p[tid] = acc / denom;
    __syncthreads();
    if (tid < MLP_DIM) {
        float a = fc1b[tid];
        for (int k = 0; k < 192; k++) a = fmaf(p[k], fc1w[k * 128 + tid], a);
        hid[tid] = fmaxf(a, 0.f);
    }
    __syncthreads();
    if (tid < N_CLASSES) {
        float a = fc2b[tid];
        for (int k = 0; k < 128; k++) a = fmaf(hid[k], fc2w[k * 10 + tid], a);
        z[tid] = a;
    }
    __syncthreads();
    if (tid == 0) {
        float m = z[0];
        for (int i = 1; i < 10; i++) m = fmaxf(m, z[i]);
        float sm = 0.f;
        for (int i = 0; i < 10; i++) sm += expf(z[i] - m);
        lse = m + logf(sm);
    }
    __syncthreads();
    if (tid < N_CLASSES) out[g * 10 + tid] = z[tid] - lse;
}

// ============================ launch ============================
extern "C" void kernel_launch(void* const* d_in, const int* in_sizes, int n_in,
                              void* d_out, int out_size, void* d_ws, size_t ws_size,
                              hipStream_t stream) {
    (void)in_sizes; (void)n_in; (void)out_size; (void)ws_size;
    const float* x    = (const float*)d_in[0];
    const int*   ei   = (const int*)d_in[1];
    const int*   batch= (const int*)d_in[2];
    const float* fc0w = (const float*)d_in[3];
    const float* fc0b = (const float*)d_in[4];
    const float* fc1w = (const float*)d_in[5];
    const float* fc1b = (const float*)d_in[6];
    const float* fc2w = (const float*)d_in[7];
    const float* fc2b = (const float*)d_in[8];
    const int* src = ei;
    const int* dst = ei + N_EDGES;
    float* out = (float*)d_out;

    char* w = (char*)d_ws;
    size_t off = 0;
    auto alloc = [&](size_t bytes) -> void* {
        void* p = w + off;
        off = (off + bytes + 255) & ~(size_t)255;
        return p;
    };
    const size_t MAX_PAD_EDGES = (size_t)N_EDGES + 16 * (size_t)N_NODES;

    // zeroed-every-launch block: gcur[NB] | gtotal | bns[3][NSLICE][128]
    const size_t BNS_OFF = 1280;
    const size_t ZBYTES  = BNS_OFF + 3 * NSLICE * 128 * 4;
    char* zbase = (char*)alloc(ZBYTES);
    int*   gcur   = (int*)zbase;                     // NB ints (bucket cursors = final counts)
    int*   gtotal = (int*)(zbase + 1024);            // sort2 ticket
    float* bnsAll = (float*)(zbase + BNS_OFF);       // 3 * NSLICE * 128 floats

    unsigned short* cat0 = (unsigned short*)alloc((size_t)N_NODES * 64 * 2);  // 6.4 MB/plane (f16)
    unsigned short* cat1 = (unsigned short*)alloc((size_t)N_NODES * 64 * 2);
    unsigned short* cat2 = (unsigned short*)alloc((size_t)N_NODES * 64 * 2);
    unsigned short* h0   = (unsigned short*)alloc((size_t)N_NODES * 64 * 2);
    unsigned short* Ae   = (unsigned short*)alloc((size_t)N_NODES * 64 * 2);
    unsigned short* Be   = (unsigned short*)alloc((size_t)N_NODES * 64 * 2);
    unsigned* keys = (unsigned*)alloc((size_t)NB * CAPB * 4);    // 12.85 MB
    unsigned short* sorted_src = (unsigned short*)alloc(MAX_PAD_EDGES * 2);  // 4.8 MB
    int*   cnt       = (int*)alloc((size_t)N_NODES * 4);   // plain-written in sort2
    int*   row_start = (int*)alloc((size_t)N_NODES * 4);

    (void)hipMemsetAsync(zbase, 0, ZBYTES, stream);

    // D1: pass1 + fc0 fused (independent; pass1 hides under fc0)
    fc0_pass1_kernel<<<NPASS1 + NFC0, 256, 0, stream>>>(src, dst, gcur, keys,
                                                        x, fc0w, fc0b, h0, bnsAll);
    // D2: sort-finish (hist+scan+ticket+scatter+fill) + ab(block 0) fused
    sort2_ab_kernel<<<NB + NFC0, 256, 0, stream>>>(
        keys, gcur, cnt, gtotal, row_start, sorted_src,
        h0, bnsAll,
        (const float*)d_in[9], (const float*)d_in[10],
        (const float*)d_in[11], (const float*)d_in[12], Ae, Be);

    unsigned short* planes[3] = {cat0, cat1, cat2};
    for (int blk = 0; blk < 3; blk++) {
        const float* w2 = (const float*)d_in[13 + 6 * blk];
        const float* b2 = (const float*)d_in[14 + 6 * blk];
        if (blk > 0) {
            ab_mfma_kernel<<<NFC0, 256, 0, stream>>>(
                planes[blk - 1], bnsAll + blk * NSLICE * 128,
                (const float*)d_in[9 + 6 * blk], (const float*)d_in[10 + 6 * blk],
                (const float*)d_in[11 + 6 * blk], (const float*)d_in[12 + 6 * blk], Ae, Be);
        }
        edge_mfma_kernel<<<2048, 256, 0, stream>>>(
            Ae, Be, row_start, cnt, sorted_src, w2, b2, planes[blk],
            (blk < 2) ? (bnsAll + (blk + 1) * NSLICE * 128) : nullptr);
    }

    poolhead_kernel<<<N_GRAPHS, 192, 0, stream>>>(cat0, cat1, cat2, batch,
                                                  fc1w, fc1b, fc2w, fc2b, out);
}